// Round 4
// baseline (1620.616 us; speedup 1.0000x reference)
//
#include <hip/hip_runtime.h>
#include <math.h>
#include <stdint.h>
#include <stddef.h>

// TreeEnergyLoss on gfx950 — R4: single-wave latency-chain kernels.
//
//  * k_bfs/k_dp use 64-thread (single-wave) workgroups: s_barrier is free for
//    a 1-wave group, leaving only the lgkmcnt wait we need for LDS ordering.
//  * BFS: one sync per level via per-level counter array; (pd<<14)|node packed
//    frontier entries.
//  * DP: ppos in LDS; edge weights prefetched one level ahead (static schedule).
//  * MST matches host Kruskal: exact float64 weights, stable tie-break.
//  * Filter is root/orientation independent => root at node 0.

namespace {
constexpr int Bn  = 4, Cc = 21, Hh = 96, Ww = 96;
constexpr int Nn  = Hh * Ww;              // 9216
constexpr int EhE = Hh * (Ww - 1);        // 9120
constexpr int Ne  = EhE + (Hh - 1) * Ww;  // 18240
constexpr int Clow = 3, Chigh = 512;
constexpr int NCh = Cc + 1;               // 22
constexpr int MAXD = 2048;

// workspace layout (bytes) — all offsets 16B-aligned
constexpr size_t OFF_ACC  = 0;                                        // 2 doubles
constexpr size_t OFF_PROB = 256;                                      // float[B][21][Nn]
constexpr size_t OFF_S1   = OFF_PROB + (size_t)Bn * Cc * Nn * 4;      // float[B][22][Nn]
constexpr size_t OFF_S2   = OFF_S1   + (size_t)Bn * NCh * Nn * 4;     // float[B][22][Nn]
constexpr size_t OFF_EW   = OFF_S2   + (size_t)Bn * NCh * Nn * 4;     // double[8][Ne]
constexpr size_t OFF_ORD  = OFF_EW   + (size_t)8 * Ne * 8;            // int[8][Nn]
constexpr size_t OFF_PPOS = OFF_ORD  + (size_t)8 * Nn * 4;            // ushort[8][Nn]
constexpr size_t OFF_WGT  = OFF_PPOS + (size_t)8 * Nn * 2;            // float[8][Nn]
constexpr size_t OFF_LEV  = OFF_WGT  + (size_t)8 * Nn * 4;            // int[8][MAXD]
constexpr size_t OFF_D    = OFF_LEV  + (size_t)8 * MAXD * 4;          // int[8]
constexpr size_t OFF_DIR  = OFF_D    + 256;                           // int[8][Nn]
constexpr size_t OFF_CBW  = OFF_DIR  + (size_t)8 * Nn * 4;            // ull[8][Nn]
constexpr size_t OFF_CBE  = OFF_CBW  + (size_t)8 * Nn * 8;            // int[8][Nn]
} // namespace

// edge id -> endpoints, matching reference concatenate([eh, ev]) ordering
__device__ __forceinline__ void edge_nodes(int e, int& a, int& b) {
    if (e < EhE) { int h = e / (Ww - 1), w = e - h * (Ww - 1); a = h * Ww + w; b = a + 1; }
    else { int e2 = e - EhE; int h = e2 / Ww, w = e2 - h * Ww; a = h * Ww + w; b = a + Ww; }
}
// dirs: 0=E(+1) 1=W(-1) 2=S(+96) 3=N(-96); rev(d)=d^1
__device__ __forceinline__ int dir_delta(int d) {
    return (d == 0) ? 1 : (d == 1) ? -1 : (d == 2) ? Ww : -Ww;
}
__device__ __forceinline__ int edge_of(int u, int d) {
    int h = u / Ww, w = u - h * Ww;
    if (d == 0) return h * (Ww - 1) + w;
    if (d == 1) return h * (Ww - 1) + w - 1;
    if (d == 2) return EhE + u;
    return EhE + u - Ww;
}

__device__ __forceinline__ int uf_find16(unsigned short* uf, int x) {
    while (true) {
        int p = uf[x];
        if (p == x) return x;
        int gp = uf[p];
        if (gp != p) uf[x] = (unsigned short)gp;  // path halving (benign races)
        x = gp;
    }
}

__global__ void k_init(const float* __restrict__ preds, float* __restrict__ prob,
                       double* __restrict__ acc) {
    int idx = blockIdx.x * blockDim.x + threadIdx.x;
    if (idx == 0) { acc[0] = 0.0; acc[1] = 0.0; }
    if (idx >= Bn * Cc * Nn) return;
    prob[idx] = 1.0f / (1.0f + expf(-preds[idx]));
}

// exact float64 edge weights: sequential channel sum matches numpy axis-0 reduce
__global__ void k_edgew(const float* __restrict__ feat, int C, double* __restrict__ ew) {
    int idx = blockIdx.x * blockDim.x + threadIdx.x;
    if (idx >= Bn * Ne) return;
    int b = idx / Ne, e = idx - b * Ne;
    int a, c2; edge_nodes(e, a, c2);
    const float* f = feat + (size_t)b * C * Nn;
    double s = 0.0;
    for (int c = 0; c < C; c++) {
        double d = (double)f[(size_t)c * Nn + a] - (double)f[(size_t)c * Nn + c2];
        s += d * d;
    }
    ew[idx] = s;
}

// Boruvka MST; emits per-node dir bitmask. One block per (tree,batch) tb.
__global__ void __launch_bounds__(1024)
k_mst(char* __restrict__ ws) {
    const int tb = blockIdx.x, tid = threadIdx.x;
    const double* ew = (const double*)(ws + OFF_EW) + (size_t)tb * Ne;
    unsigned long long* cbW = (unsigned long long*)(ws + OFF_CBW) + (size_t)tb * Nn;
    int* cbE  = (int*)(ws + OFF_CBE)  + (size_t)tb * Nn;
    int* dirG = (int*)(ws + OFF_DIR)  + (size_t)tb * Nn;

    __shared__ unsigned short uf[Nn], comp[Nn], nxt[Nn];
    __shared__ int sMst, chgArr[48];

    if (tid == 0) sMst = 0;
    for (int i = tid; i < Nn; i += 1024) { uf[i] = (unsigned short)i; dirG[i] = 0; }
    __syncthreads();

    for (int round = 0; round < 24; round++) {
        if (sMst >= Nn - 1) break;
        for (int i = tid; i < Nn; i += 1024) {
            cbW[i] = ~0ull; cbE[i] = 0x7fffffff;
            comp[i] = (unsigned short)uf_find16(uf, i);
        }
        if (tid < 48) chgArr[tid] = 0;
        __syncthreads();
        // pass 1: min weight bits per component
        for (int e = tid; e < Ne; e += 1024) {
            int a, c; edge_nodes(e, a, c);
            int ra = comp[a], rb = comp[c];
            if (ra != rb) {
                unsigned long long wb = (unsigned long long)__double_as_longlong(ew[e]);
                atomicMin(&cbW[ra], wb); atomicMin(&cbW[rb], wb);
            }
        }
        __syncthreads();
        // pass 2: min edge index among exact-min-weight edges (stable tie-break)
        for (int e = tid; e < Ne; e += 1024) {
            int a, c; edge_nodes(e, a, c);
            int ra = comp[a], rb = comp[c];
            if (ra != rb) {
                unsigned long long wb = (unsigned long long)__double_as_longlong(ew[e]);
                if (wb == cbW[ra]) atomicMin(&cbE[ra], e);
                if (wb == cbW[rb]) atomicMin(&cbE[rb], e);
            }
        }
        __syncthreads();
        // select + dedupe (no global mstf): edge counted once by its smaller
        // selector (or its unique selector); dir-bit atomicOr is idempotent.
        for (int r = tid; r < Nn; r += 1024) {
            if (comp[r] == r) {
                int e = cbE[r];
                if (e != 0x7fffffff) {
                    int a, c; edge_nodes(e, a, c);
                    int ra = comp[a], rb = comp[c];
                    int other = (ra == r) ? rb : ra;
                    nxt[r] = (unsigned short)other;
                    if (cbE[other] != e || r < other) {
                        atomicAdd(&sMst, 1);
                        int da = (c == a + 1) ? 0 : 2;           // E or S from a
                        atomicOr(&dirG[a], 1 << da);
                        atomicOr(&dirG[c], 1 << (da ^ 1));       // W or N from c
                    }
                } else nxt[r] = (unsigned short)r;
            }
        }
        __syncthreads();
        // break 2-cycles
        for (int r = tid; r < Nn; r += 1024) {
            if (comp[r] == r) {
                int o = nxt[r];
                if (o != r && nxt[o] == r && r < o) nxt[r] = (unsigned short)r;
            }
        }
        __syncthreads();
        // pointer jumping, one barrier per iteration via per-iter flag slots
        int it = 0;
        while (it < 40) {
            bool any = false;
            for (int r = tid; r < Nn; r += 1024) {
                if (comp[r] == r) {
                    int nr = nxt[r], nnr = nxt[nr];
                    if (nr != nnr) { nxt[r] = (unsigned short)nnr; any = true; }
                }
            }
            if (any) chgArr[it] = 1;
            __syncthreads();
            if (!chgArr[it]) break;
            it++;
        }
        for (int r = tid; r < Nn; r += 1024)
            if (comp[r] == r) uf[r] = nxt[r];
        __syncthreads();
    }
}

// Single-wave BFS from node 0; one barrier per level; flat post-pass.
__global__ void __launch_bounds__(64)
k_bfs(char* __restrict__ ws) {
    const int tb = blockIdx.x, lane = threadIdx.x;
    const int tree = tb >> 2;
    const double* ew = (const double*)(ws + OFF_EW) + (size_t)tb * Ne;
    const int* dirG = (const int*)(ws + OFF_DIR) + (size_t)tb * Nn;
    int*            ordG  = (int*)(ws + OFF_ORD)  + (size_t)tb * Nn;
    unsigned short* pposG = (unsigned short*)(ws + OFF_PPOS) + (size_t)tb * Nn;
    float*          wgtG  = (float*)(ws + OFF_WGT) + (size_t)tb * Nn;
    int*            levG  = (int*)(ws + OFF_LEV)  + (size_t)tb * MAXD;
    int*            dG    = (int*)(ws + OFF_D);
    const float inv_sigma = tree ? 1.0f : 50.0f;

    __shared__ alignas(16) unsigned short ordS[Nn];   // (pd<<14) | node
    __shared__ alignas(16) unsigned short posOf[Nn];
    __shared__ alignas(16) unsigned char  nbS[Nn];
    __shared__ int cntS[MAXD];
    __shared__ unsigned short levS[MAXD];

    {   // dir masks -> LDS bytes (vectorized)
        const int4* d4 = (const int4*)dirG;
        for (int k = lane; k < Nn / 4; k += 64) {
            int4 t = d4[k];
            nbS[4 * k]     = (unsigned char)t.x;
            nbS[4 * k + 1] = (unsigned char)t.y;
            nbS[4 * k + 2] = (unsigned char)t.z;
            nbS[4 * k + 3] = (unsigned char)t.w;
        }
    }
    for (int k = lane; k < MAXD; k += 64) cntS[k] = 0;
    if (lane == 0) { ordS[0] = 0; levS[0] = 0; levS[1] = 1; }
    __syncthreads();

    int cs = 0, ce = 1, L = 0;
    while (ce < Nn && L < MAXD - 2) {
        for (int i = cs + lane; i < ce; i += 64) {
            int ent = ordS[i];
            int u = ent & 0x3FFF;
            int pd = (i == 0) ? 15 : (ent >> 14);
            int m = nbS[u];
            #pragma unroll
            for (int dd = 0; dd < 4; dd++) {
                if (((m >> dd) & 1) && dd != pd) {
                    int v = u + dir_delta(dd);
                    int pos = ce + atomicAdd(&cntS[L + 1], 1);
                    ordS[pos] = (unsigned short)(((dd ^ 1) << 14) | v);
                }
            }
        }
        __syncthreads();   // level L+1 counts final; future adds go to L+2
        int k = cntS[L + 1];
        cs = ce; ce += k; L++;
        if (lane == 0) levS[L + 1] = (unsigned short)ce;
    }
    const int D = L + 1;
    __syncthreads();

    // flat post-pass: inverse permutation, weights, outputs
    for (int i = lane; i < Nn; i += 64) posOf[ordS[i] & 0x3FFF] = (unsigned short)i;
    __syncthreads();
    for (int i = lane; i < Nn; i += 64) {
        int ent = ordS[i];
        int u = ent & 0x3FFF;
        ordG[i] = u;
        if (i == 0) { pposG[0] = 0; wgtG[0] = 0.0f; }
        else {
            int pd = ent >> 14;
            int p = u + dir_delta(pd);
            int e = edge_of(u, pd);
            wgtG[i] = expf(-(float)ew[e] * inv_sigma);
            pposG[i] = posOf[p];
        }
    }
    if (lane == 0) dG[tb] = D;
    for (int d = lane; d <= D; d += 64) levG[d] = levS[d];
}

// Single-wave two-pass tree DP for one (batch, channel); wgt prefetched.
__global__ void __launch_bounds__(64)
k_dp(char* __restrict__ ws, int tree, int inMode) {
    const int bc = blockIdx.x;
    const int b = bc / NCh, c = bc % NCh;
    const int tb = tree * Bn + b;
    const int lane = threadIdx.x;
    const int*            ordG  = (const int*)(ws + OFF_ORD)  + (size_t)tb * Nn;
    const unsigned short* pposG = (const unsigned short*)(ws + OFF_PPOS) + (size_t)tb * Nn;
    const float*          wgtG  = (const float*)(ws + OFF_WGT) + (size_t)tb * Nn;
    const int*            levG  = (const int*)(ws + OFF_LEV)  + (size_t)tb * MAXD;
    const int D = ((const int*)(ws + OFF_D))[tb];
    const float* src = (inMode == 0)
        ? (const float*)(ws + OFF_PROB) + ((size_t)b * Cc + c) * Nn
        : (const float*)(ws + OFF_S1)   + ((size_t)b * NCh + c) * Nn;
    float* dst = (float*)(ws + (tree ? OFF_S2 : OFF_S1)) + ((size_t)b * NCh + c) * Nn;

    __shared__ alignas(16) float Al[Nn];
    __shared__ alignas(16) unsigned short pposS[Nn];
    __shared__ unsigned short levS[MAXD];

    {   // ppos -> LDS (8 ushorts per 16B load)
        const uint4* pg4 = (const uint4*)pposG;
        uint4* ps4 = (uint4*)pposS;
        for (int k = lane; k < Nn / 8; k += 64) ps4[k] = pg4[k];
    }
    for (int d = lane; d <= D; d += 64) levS[d] = (unsigned short)levG[d];
    if (c == Cc) { for (int i = lane; i < Nn; i += 64) Al[i] = 1.0f; }
    else         { for (int i = lane; i < Nn; i += 64) Al[i] = src[ordG[i]]; }
    __syncthreads();

    // up: children before parents (ds_add_f32, no return — off the chain)
    {
        int d = D - 1;
        int s0 = levS[d], s1 = levS[d + 1];
        float wq = (s0 + lane < s1) ? wgtG[s0 + lane] : 0.0f;
        for (; d >= 1; d--) {
            s0 = levS[d]; s1 = levS[d + 1];
            float wq_next = 0.0f;
            if (d > 1) {
                int p0 = levS[d - 1];
                if (p0 + lane < s0) wq_next = wgtG[p0 + lane];
            }
            int i = s0 + lane;
            if (i < s1) atomicAdd(&Al[pposS[i]], wq * Al[i]);
            for (i = s0 + lane + 64; i < s1; i += 64)
                atomicAdd(&Al[pposS[i]], wgtG[i] * Al[i]);
            __syncthreads();
            wq = wq_next;
        }
    }
    // down: parents before children
    if (D > 1) {
        int s0 = levS[1], s1 = levS[2 <= D ? 2 : 1];
        float wq = (s0 + lane < s1) ? wgtG[s0 + lane] : 0.0f;
        for (int d = 1; d < D; d++) {
            s0 = levS[d]; s1 = levS[d + 1];
            float wq_next = 0.0f;
            if (d + 1 < D) {
                int n0 = levS[d + 1], n1 = levS[d + 2];
                if (n0 + lane < n1) wq_next = wgtG[n0 + lane];
            }
            int i = s0 + lane;
            if (i < s1) { float w = wq, a = Al[i]; Al[i] = a + w * (Al[pposS[i]] - w * a); }
            for (i = s0 + lane + 64; i < s1; i += 64) {
                float w = wgtG[i], a = Al[i];
                Al[i] = a + w * (Al[pposS[i]] - w * a);
            }
            __syncthreads();
            wq = wq_next;
        }
    }
    for (int i = lane; i < Nn; i += 64) dst[ordG[i]] = Al[i];
}

// normalize S1 channels by norm channel (flat; removes work from dp2 gather)
__global__ void k_norm(char* __restrict__ ws) {
    int idx = blockIdx.x * 256 + threadIdx.x;
    if (idx >= Bn * Cc * Nn) return;
    int b = idx / (Cc * Nn), rem = idx - b * (Cc * Nn);
    int c = rem / Nn, n = rem - c * Nn;
    float* S1 = (float*)(ws + OFF_S1);
    S1[((size_t)b * NCh + c) * Nn + n] /= S1[((size_t)b * NCh + Cc) * Nn + n];
}

__global__ void k_loss(char* __restrict__ ws, const float* __restrict__ roi) {
    const int tid = threadIdx.x;
    int idx = blockIdx.x * 256 + tid;
    const float* prob = (const float*)(ws + OFF_PROB);
    const float* S2   = (const float*)(ws + OFF_S2);
    double* acc = (double*)(ws + OFF_ACC);
    double ls = 0.0, cnt = 0.0;
    if (idx < Bn * Cc * Nn) {
        int b = idx / (Cc * Nn);
        int rem = idx - b * (Cc * Nn);
        int c = rem / Nn, n = rem - c * Nn;
        int h = n / Ww, w2 = n - h * Ww;
        float r = roi[(size_t)b * (2 * Hh) * (2 * Ww) + (size_t)(2 * h) * (2 * Ww) + 2 * w2];
        float as = S2[((size_t)b * NCh + c) * Nn + n] / S2[((size_t)b * NCh + Cc) * Nn + n];
        float pp = prob[((size_t)b * Cc + c) * Nn + n];
        ls = (double)(r * fabsf(pp - as));
        if (c == 0) cnt = (double)r;
    }
    __shared__ double sl[256], sc2[256];
    sl[tid] = ls; sc2[tid] = cnt;
    __syncthreads();
    for (int s = 128; s > 0; s >>= 1) {
        if (tid < s) { sl[tid] += sl[tid + s]; sc2[tid] += sc2[tid + s]; }
        __syncthreads();
    }
    if (tid == 0) { atomicAdd(acc, sl[0]); atomicAdd(acc + 1, sc2[0]); }
}

__global__ void k_final(const double* __restrict__ acc, float* __restrict__ out) {
    if (blockIdx.x == 0 && threadIdx.x == 0)
        out[0] = (acc[1] > 0.0) ? (float)(acc[0] / acc[1]) : 0.0f;
}

extern "C" void kernel_launch(void* const* d_in, const int* in_sizes, int n_in,
                              void* d_out, int out_size, void* d_ws, size_t ws_size,
                              hipStream_t stream) {
    const float* preds = (const float*)d_in[0];
    const float* lowf  = (const float*)d_in[1];
    const float* highf = (const float*)d_in[2];
    const float* roi   = (const float*)d_in[3];
    char* ws = (char*)d_ws;
    float* out = (float*)d_out;
    double* ewl = (double*)(ws + OFF_EW);                      // tb 0..3 (low tree)
    double* ewh = (double*)(ws + OFF_EW) + (size_t)Bn * Ne;    // tb 4..7 (high tree)

    k_init<<<(Bn * Cc * Nn + 255) / 256, 256, 0, stream>>>(
        preds, (float*)(ws + OFF_PROB), (double*)(ws + OFF_ACC));
    k_edgew<<<(Bn * Ne + 255) / 256, 256, 0, stream>>>(lowf, Clow, ewl);
    k_edgew<<<(Bn * Ne + 255) / 256, 256, 0, stream>>>(highf, Chigh, ewh);
    k_mst<<<8, 1024, 0, stream>>>(ws);
    k_bfs<<<8, 64, 0, stream>>>(ws);
    k_dp<<<Bn * NCh, 64, 0, stream>>>(ws, 0, 0);
    k_norm<<<(Bn * Cc * Nn + 255) / 256, 256, 0, stream>>>(ws);
    k_dp<<<Bn * NCh, 64, 0, stream>>>(ws, 1, 1);
    k_loss<<<(Bn * Cc * Nn + 255) / 256, 256, 0, stream>>>(ws, roi);
    k_final<<<1, 64, 0, stream>>>((const double*)(ws + OFF_ACC), out);
}

// Round 5
// 1588.234 us; speedup vs baseline: 1.0204x; 1.0204x over previous
//
#include <hip/hip_runtime.h>
#include <math.h>
#include <stdint.h>
#include <stddef.h>

// TreeEnergyLoss on gfx950 — R5: BFS chain-shortening + Boruvka edge compaction.
//
//  * k_bfs: 256 threads, ONE barrier/level (ring counters), frontier entries
//    carry their child mask (kills the dependent nbS read on the chain).
//  * k_mst: round 1 = flat per-node min over <=4 incident edges (no atomics);
//    rounds >=2 sweep a compacted inter-component edge list (ushort, overlaid
//    on the dead ORD/WGT regions). Termination = empty edge list.
//  * k_dp unchanged from R4 (single wave, prefetched weights).
//  * MST matches host Kruskal: exact float64 weights, stable tie-break.

namespace {
constexpr int Bn  = 4, Cc = 21, Hh = 96, Ww = 96;
constexpr int Nn  = Hh * Ww;              // 9216
constexpr int EhE = Hh * (Ww - 1);        // 9120
constexpr int Ne  = EhE + (Hh - 1) * Ww;  // 18240
constexpr int Clow = 3, Chigh = 512;
constexpr int NCh = Cc + 1;               // 22
constexpr int MAXD = 2048;

// workspace layout (bytes) — all offsets 16B-aligned
constexpr size_t OFF_ACC  = 0;                                        // 2 doubles
constexpr size_t OFF_PROB = 256;                                      // float[B][21][Nn]
constexpr size_t OFF_S1   = OFF_PROB + (size_t)Bn * Cc * Nn * 4;      // float[B][22][Nn]
constexpr size_t OFF_S2   = OFF_S1   + (size_t)Bn * NCh * Nn * 4;     // float[B][22][Nn]
constexpr size_t OFF_EW   = OFF_S2   + (size_t)Bn * NCh * Nn * 4;     // double[8][Ne]
constexpr size_t OFF_ORD  = OFF_EW   + (size_t)8 * Ne * 8;            // int[8][Nn]
constexpr size_t OFF_PPOS = OFF_ORD  + (size_t)8 * Nn * 4;            // ushort[8][Nn]
constexpr size_t OFF_WGT  = OFF_PPOS + (size_t)8 * Nn * 2;            // float[8][Nn]
constexpr size_t OFF_LEV  = OFF_WGT  + (size_t)8 * Nn * 4;            // int[8][MAXD]
constexpr size_t OFF_D    = OFF_LEV  + (size_t)8 * MAXD * 4;          // int[8]
constexpr size_t OFF_DIR  = OFF_D    + 256;                           // int[8][Nn]
constexpr size_t OFF_CBW  = OFF_DIR  + (size_t)8 * Nn * 4;            // ull[8][Nn]
constexpr size_t OFF_CBE  = OFF_CBW  + (size_t)8 * Nn * 8;            // int[8][Nn]
// edge-list ping/pong for k_mst overlaid on regions dead until k_bfs:
constexpr size_t OFF_EL1  = OFF_ORD;                                  // ushort[8][Ne]
constexpr size_t OFF_EL2  = OFF_WGT;                                  // ushort[8][Ne]
} // namespace

// edge id -> endpoints, matching reference concatenate([eh, ev]) ordering
__device__ __forceinline__ void edge_nodes(int e, int& a, int& b) {
    if (e < EhE) { int h = e / (Ww - 1), w = e - h * (Ww - 1); a = h * Ww + w; b = a + 1; }
    else { int e2 = e - EhE; int h = e2 / Ww, w = e2 - h * Ww; a = h * Ww + w; b = a + Ww; }
}
// dirs: 0=E(+1) 1=W(-1) 2=S(+96) 3=N(-96); rev(d)=d^1
__device__ __forceinline__ int dir_delta(int d) {
    return (d == 0) ? 1 : (d == 1) ? -1 : (d == 2) ? Ww : -Ww;
}
__device__ __forceinline__ int edge_of(int u, int d) {
    int h = u / Ww, w = u - h * Ww;
    if (d == 0) return h * (Ww - 1) + w;
    if (d == 1) return h * (Ww - 1) + w - 1;
    if (d == 2) return EhE + u;
    return EhE + u - Ww;
}

__device__ __forceinline__ int uf_find16(unsigned short* uf, int x) {
    while (true) {
        int p = uf[x];
        if (p == x) return x;
        int gp = uf[p];
        if (gp != p) uf[x] = (unsigned short)gp;  // path halving (benign races)
        x = gp;
    }
}

__global__ void k_init(const float* __restrict__ preds, float* __restrict__ prob,
                       double* __restrict__ acc) {
    int idx = blockIdx.x * blockDim.x + threadIdx.x;
    if (idx == 0) { acc[0] = 0.0; acc[1] = 0.0; }
    if (idx >= Bn * Cc * Nn) return;
    prob[idx] = 1.0f / (1.0f + expf(-preds[idx]));
}

// exact float64 edge weights: sequential channel sum matches numpy axis-0 reduce
__global__ void k_edgew(const float* __restrict__ feat, int C, double* __restrict__ ew) {
    int idx = blockIdx.x * blockDim.x + threadIdx.x;
    if (idx >= Bn * Ne) return;
    int b = idx / Ne, e = idx - b * Ne;
    int a, c2; edge_nodes(e, a, c2);
    const float* f = feat + (size_t)b * C * Nn;
    double s = 0.0;
    for (int c = 0; c < C; c++) {
        double d = (double)f[(size_t)c * Nn + a] - (double)f[(size_t)c * Nn + c2];
        s += d * d;
    }
    ew[idx] = s;
}

// Boruvka MST; emits per-node dir bitmask. One block per (tree,batch) tb.
// Round 1: flat per-node min over incident edges. Rounds>=2: compacted lists.
__global__ void __launch_bounds__(1024)
k_mst(char* __restrict__ ws) {
    const int tb = blockIdx.x, tid = threadIdx.x;
    const double* ew = (const double*)(ws + OFF_EW) + (size_t)tb * Ne;
    unsigned long long* cbW = (unsigned long long*)(ws + OFF_CBW) + (size_t)tb * Nn;
    int* cbE  = (int*)(ws + OFF_CBE)  + (size_t)tb * Nn;
    int* dirG = (int*)(ws + OFF_DIR)  + (size_t)tb * Nn;
    unsigned short* elA = (unsigned short*)(ws + OFF_EL1) + (size_t)tb * Ne;
    unsigned short* elB = (unsigned short*)(ws + OFF_EL2) + (size_t)tb * Ne;

    __shared__ unsigned short uf[Nn], comp[Nn], nxt[Nn];
    __shared__ int chgArr[48];
    __shared__ int sLen;

    for (int i = tid; i < Nn; i += 1024) { uf[i] = (unsigned short)i; dirG[i] = 0; }
    if (tid < 48) chgArr[tid] = 0;
    __syncthreads();

    // ---------- round 1: every node picks its min incident edge ----------
    for (int i = tid; i < Nn; i += 1024) {
        int h = i / Ww, w = i - h * Ww;
        unsigned long long bw = ~0ull; int be = 0x7fffffff;
        // E, W, S, N candidate edges
        int cand[4]; int nc = 0;
        if (w < Ww - 1) cand[nc++] = h * (Ww - 1) + w;
        if (w > 0)      cand[nc++] = h * (Ww - 1) + w - 1;
        if (h < Hh - 1) cand[nc++] = EhE + i;
        if (h > 0)      cand[nc++] = EhE + i - Ww;
        for (int k = 0; k < nc; k++) {
            int e = cand[k];
            unsigned long long wb = (unsigned long long)__double_as_longlong(ew[e]);
            if (wb < bw || (wb == bw && e < be)) { bw = wb; be = e; }
        }
        cbE[i] = be;
    }
    __syncthreads();
    for (int i = tid; i < Nn; i += 1024) {
        int e = cbE[i];
        int a, c; edge_nodes(e, a, c);
        nxt[i] = (unsigned short)((a == i) ? c : a);
        int da = (c == a + 1) ? 0 : 2;                 // E or S from a
        atomicOr(&dirG[a], 1 << da);                   // idempotent marks
        atomicOr(&dirG[c], 1 << (da ^ 1));
    }
    __syncthreads();
    for (int i = tid; i < Nn; i += 1024) {             // break 2-cycles
        int o = nxt[i];
        if (o != i && nxt[o] == i && i < o) nxt[i] = (unsigned short)i;
    }
    __syncthreads();
    {   // pointer jumping over all nodes
        int it = 0;
        while (it < 40) {
            bool any = false;
            for (int r = tid; r < Nn; r += 1024) {
                int nr = nxt[r], nnr = nxt[nr];
                if (nr != nnr) { nxt[r] = (unsigned short)nnr; any = true; }
            }
            if (any) chgArr[it] = 1;
            __syncthreads();
            if (!chgArr[it]) break;
            it++;
        }
        for (int r = tid; r < Nn; r += 1024) uf[r] = nxt[r];
        __syncthreads();
    }

    // ---------- rounds >= 2: compacted edge lists ----------
    unsigned short* src = elA;  // filled by compaction below
    unsigned short* dst = elB;
    int srcLen = -1;            // -1: source is the implicit full range
    for (int round = 2; round < 20; round++) {
        for (int i = tid; i < Nn; i += 1024)
            comp[i] = (unsigned short)uf_find16(uf, i);
        if (tid == 0) sLen = 0;
        if (tid < 48) chgArr[tid] = 0;
        __syncthreads();
        // compact surviving inter-component edges
        if (srcLen < 0) {
            for (int e = tid; e < Ne; e += 1024) {
                int a, c; edge_nodes(e, a, c);
                if (comp[a] != comp[c]) dst[atomicAdd(&sLen, 1)] = (unsigned short)e;
            }
        } else {
            for (int k = tid; k < srcLen; k += 1024) {
                int e = src[k];
                int a, c; edge_nodes(e, a, c);
                if (comp[a] != comp[c]) dst[atomicAdd(&sLen, 1)] = (unsigned short)e;
            }
        }
        __syncthreads();
        int len = sLen;
        if (len == 0) break;                           // single component: done
        for (int i = tid; i < Nn; i += 1024) { cbW[i] = ~0ull; cbE[i] = 0x7fffffff; }
        __syncthreads();
        // pass 1: min weight bits per component
        for (int k = tid; k < len; k += 1024) {
            int e = dst[k];
            int a, c; edge_nodes(e, a, c);
            unsigned long long wb = (unsigned long long)__double_as_longlong(ew[e]);
            atomicMin(&cbW[comp[a]], wb); atomicMin(&cbW[comp[c]], wb);
        }
        __syncthreads();
        // pass 2: min edge index among exact-min-weight edges (stable tie-break)
        for (int k = tid; k < len; k += 1024) {
            int e = dst[k];
            int a, c; edge_nodes(e, a, c);
            unsigned long long wb = (unsigned long long)__double_as_longlong(ew[e]);
            if (wb == cbW[comp[a]]) atomicMin(&cbE[comp[a]], e);
            if (wb == cbW[comp[c]]) atomicMin(&cbE[comp[c]], e);
        }
        __syncthreads();
        // select + mark
        for (int r = tid; r < Nn; r += 1024) {
            if (comp[r] == r) {
                int e = cbE[r];
                if (e != 0x7fffffff) {
                    int a, c; edge_nodes(e, a, c);
                    nxt[r] = (unsigned short)((comp[a] == r) ? comp[c] : comp[a]);
                    int da = (c == a + 1) ? 0 : 2;
                    atomicOr(&dirG[a], 1 << da);
                    atomicOr(&dirG[c], 1 << (da ^ 1));
                } else nxt[r] = (unsigned short)r;
            }
        }
        __syncthreads();
        for (int r = tid; r < Nn; r += 1024) {         // break 2-cycles
            if (comp[r] == r) {
                int o = nxt[r];
                if (o != r && nxt[o] == r && r < o) nxt[r] = (unsigned short)r;
            }
        }
        __syncthreads();
        int it = 0;
        while (it < 40) {                               // pointer jumping (roots)
            bool any = false;
            for (int r = tid; r < Nn; r += 1024) {
                if (comp[r] == r) {
                    int nr = nxt[r], nnr = nxt[nr];
                    if (nr != nnr) { nxt[r] = (unsigned short)nnr; any = true; }
                }
            }
            if (any) chgArr[it] = 1;
            __syncthreads();
            if (!chgArr[it]) break;
            it++;
        }
        for (int r = tid; r < Nn; r += 1024)
            if (comp[r] == r) uf[r] = nxt[r];
        __syncthreads();
        // swap lists
        unsigned short* t = src; src = dst; dst = t;
        srcLen = len;
    }
}

// BFS from node 0: 256 threads, one barrier per level, child-mask-carrying
// frontier entries, ring level-counters. Flat post-pass emits outputs.
__global__ void __launch_bounds__(256)
k_bfs(char* __restrict__ ws) {
    const int tb = blockIdx.x, tid = threadIdx.x;
    const int tree = tb >> 2;
    const double* ew = (const double*)(ws + OFF_EW) + (size_t)tb * Ne;
    const int* dirG = (const int*)(ws + OFF_DIR) + (size_t)tb * Nn;
    int*            ordG  = (int*)(ws + OFF_ORD)  + (size_t)tb * Nn;
    unsigned short* pposG = (unsigned short*)(ws + OFF_PPOS) + (size_t)tb * Nn;
    float*          wgtG  = (float*)(ws + OFF_WGT) + (size_t)tb * Nn;
    int*            levG  = (int*)(ws + OFF_LEV)  + (size_t)tb * MAXD;
    int*            dG    = (int*)(ws + OFF_D);
    const float inv_sigma = tree ? 1.0f : 50.0f;

    __shared__ alignas(16) unsigned short ordS[Nn];    // (pd<<14) | node
    __shared__ alignas(16) unsigned char  cmS[Nn];     // child-dir mask at pos
    __shared__ alignas(16) unsigned char  nbS[Nn];     // tree dir mask by node
    __shared__ alignas(16) unsigned short posOf[Nn];
    __shared__ unsigned short levS[MAXD];
    __shared__ int cnt[8];

    {   // dir masks -> LDS bytes (vectorized)
        const int4* d4 = (const int4*)dirG;
        for (int k = tid; k < Nn / 4; k += 256) {
            int4 t = d4[k];
            nbS[4 * k]     = (unsigned char)t.x;
            nbS[4 * k + 1] = (unsigned char)t.y;
            nbS[4 * k + 2] = (unsigned char)t.z;
            nbS[4 * k + 3] = (unsigned char)t.w;
        }
    }
    if (tid < 8) cnt[tid] = 0;
    __syncthreads();
    if (tid == 0) { ordS[0] = 0; cmS[0] = nbS[0]; levS[0] = 0; levS[1] = 1; }
    __syncthreads();

    int cs = 0, ce = 1, L = 0;
    while (ce < Nn && L < MAXD - 2) {
        for (int i = cs + tid; i < ce; i += 256) {
            int u = ordS[i] & 0x3FFF;
            int m = cmS[i];
            while (m) {
                int dd = __ffs(m) - 1; m &= m - 1;
                int v = u + dir_delta(dd);
                int pos = ce + atomicAdd(&cnt[(L + 1) & 7], 1);
                ordS[pos] = (unsigned short)(((dd ^ 1) << 14) | v);
                cmS[pos]  = (unsigned char)(nbS[v] & ~(1 << (dd ^ 1)));
            }
        }
        if (tid == 0) cnt[(L + 5) & 7] = 0;            // recycle far-future slot
        __syncthreads();                               // adds for L+1 complete
        int k = cnt[(L + 1) & 7];
        cs = ce; ce += k; L++;
        if (tid == 0) levS[L + 1] = (unsigned short)ce;
    }
    const int D = L + 1;
    __syncthreads();

    // flat post-pass: inverse permutation, weights, outputs
    for (int i = tid; i < Nn; i += 256) posOf[ordS[i] & 0x3FFF] = (unsigned short)i;
    __syncthreads();
    for (int i = tid; i < Nn; i += 256) {
        int ent = ordS[i];
        int u = ent & 0x3FFF;
        ordG[i] = u;
        if (i == 0) { pposG[0] = 0; wgtG[0] = 0.0f; }
        else {
            int pd = ent >> 14;
            int p = u + dir_delta(pd);
            int e = edge_of(u, pd);
            wgtG[i] = expf(-(float)ew[e] * inv_sigma);
            pposG[i] = posOf[p];
        }
    }
    if (tid == 0) dG[tb] = D;
    for (int d = tid; d <= D; d += 256) levG[d] = levS[d];
}

// Single-wave two-pass tree DP for one (batch, channel); wgt prefetched.
__global__ void __launch_bounds__(64)
k_dp(char* __restrict__ ws, int tree, int inMode) {
    const int bc = blockIdx.x;
    const int b = bc / NCh, c = bc % NCh;
    const int tb = tree * Bn + b;
    const int lane = threadIdx.x;
    const int*            ordG  = (const int*)(ws + OFF_ORD)  + (size_t)tb * Nn;
    const unsigned short* pposG = (const unsigned short*)(ws + OFF_PPOS) + (size_t)tb * Nn;
    const float*          wgtG  = (const float*)(ws + OFF_WGT) + (size_t)tb * Nn;
    const int*            levG  = (const int*)(ws + OFF_LEV)  + (size_t)tb * MAXD;
    const int D = ((const int*)(ws + OFF_D))[tb];
    const float* src = (inMode == 0)
        ? (const float*)(ws + OFF_PROB) + ((size_t)b * Cc + c) * Nn
        : (const float*)(ws + OFF_S1)   + ((size_t)b * NCh + c) * Nn;
    float* dst = (float*)(ws + (tree ? OFF_S2 : OFF_S1)) + ((size_t)b * NCh + c) * Nn;

    __shared__ alignas(16) float Al[Nn];
    __shared__ alignas(16) unsigned short pposS[Nn];
    __shared__ unsigned short levS[MAXD];

    {   // ppos -> LDS (8 ushorts per 16B load)
        const uint4* pg4 = (const uint4*)pposG;
        uint4* ps4 = (uint4*)pposS;
        for (int k = lane; k < Nn / 8; k += 64) ps4[k] = pg4[k];
    }
    for (int d = lane; d <= D; d += 64) levS[d] = (unsigned short)levG[d];
    if (c == Cc) { for (int i = lane; i < Nn; i += 64) Al[i] = 1.0f; }
    else         { for (int i = lane; i < Nn; i += 64) Al[i] = src[ordG[i]]; }
    __syncthreads();

    // up: children before parents (ds_add_f32, no return — off the chain)
    {
        int d = D - 1;
        int s0 = levS[d], s1 = levS[d + 1];
        float wq = (s0 + lane < s1) ? wgtG[s0 + lane] : 0.0f;
        for (; d >= 1; d--) {
            s0 = levS[d]; s1 = levS[d + 1];
            float wq_next = 0.0f;
            if (d > 1) {
                int p0 = levS[d - 1];
                if (p0 + lane < s0) wq_next = wgtG[p0 + lane];
            }
            int i = s0 + lane;
            if (i < s1) atomicAdd(&Al[pposS[i]], wq * Al[i]);
            for (i = s0 + lane + 64; i < s1; i += 64)
                atomicAdd(&Al[pposS[i]], wgtG[i] * Al[i]);
            __syncthreads();
            wq = wq_next;
        }
    }
    // down: parents before children
    if (D > 1) {
        int s0 = levS[1], s1 = levS[2 <= D ? 2 : 1];
        float wq = (s0 + lane < s1) ? wgtG[s0 + lane] : 0.0f;
        for (int d = 1; d < D; d++) {
            s0 = levS[d]; s1 = levS[d + 1];
            float wq_next = 0.0f;
            if (d + 1 < D) {
                int n0 = levS[d + 1], n1 = levS[d + 2];
                if (n0 + lane < n1) wq_next = wgtG[n0 + lane];
            }
            int i = s0 + lane;
            if (i < s1) { float w = wq, a = Al[i]; Al[i] = a + w * (Al[pposS[i]] - w * a); }
            for (i = s0 + lane + 64; i < s1; i += 64) {
                float w = wgtG[i], a = Al[i];
                Al[i] = a + w * (Al[pposS[i]] - w * a);
            }
            __syncthreads();
            wq = wq_next;
        }
    }
    for (int i = lane; i < Nn; i += 64) dst[ordG[i]] = Al[i];
}

// normalize S1 channels by norm channel (flat; removes work from dp2 gather)
__global__ void k_norm(char* __restrict__ ws) {
    int idx = blockIdx.x * 256 + threadIdx.x;
    if (idx >= Bn * Cc * Nn) return;
    int b = idx / (Cc * Nn), rem = idx - b * (Cc * Nn);
    int c = rem / Nn, n = rem - c * Nn;
    float* S1 = (float*)(ws + OFF_S1);
    S1[((size_t)b * NCh + c) * Nn + n] /= S1[((size_t)b * NCh + Cc) * Nn + n];
}

__global__ void k_loss(char* __restrict__ ws, const float* __restrict__ roi) {
    const int tid = threadIdx.x;
    int idx = blockIdx.x * 256 + tid;
    const float* prob = (const float*)(ws + OFF_PROB);
    const float* S2   = (const float*)(ws + OFF_S2);
    double* acc = (double*)(ws + OFF_ACC);
    double ls = 0.0, cnt = 0.0;
    if (idx < Bn * Cc * Nn) {
        int b = idx / (Cc * Nn);
        int rem = idx - b * (Cc * Nn);
        int c = rem / Nn, n = rem - c * Nn;
        int h = n / Ww, w2 = n - h * Ww;
        float r = roi[(size_t)b * (2 * Hh) * (2 * Ww) + (size_t)(2 * h) * (2 * Ww) + 2 * w2];
        float as = S2[((size_t)b * NCh + c) * Nn + n] / S2[((size_t)b * NCh + Cc) * Nn + n];
        float pp = prob[((size_t)b * Cc + c) * Nn + n];
        ls = (double)(r * fabsf(pp - as));
        if (c == 0) cnt = (double)r;
    }
    __shared__ double sl[256], sc2[256];
    sl[tid] = ls; sc2[tid] = cnt;
    __syncthreads();
    for (int s = 128; s > 0; s >>= 1) {
        if (tid < s) { sl[tid] += sl[tid + s]; sc2[tid] += sc2[tid + s]; }
        __syncthreads();
    }
    if (tid == 0) { atomicAdd(acc, sl[0]); atomicAdd(acc + 1, sc2[0]); }
}

__global__ void k_final(const double* __restrict__ acc, float* __restrict__ out) {
    if (blockIdx.x == 0 && threadIdx.x == 0)
        out[0] = (acc[1] > 0.0) ? (float)(acc[0] / acc[1]) : 0.0f;
}

extern "C" void kernel_launch(void* const* d_in, const int* in_sizes, int n_in,
                              void* d_out, int out_size, void* d_ws, size_t ws_size,
                              hipStream_t stream) {
    const float* preds = (const float*)d_in[0];
    const float* lowf  = (const float*)d_in[1];
    const float* highf = (const float*)d_in[2];
    const float* roi   = (const float*)d_in[3];
    char* ws = (char*)d_ws;
    float* out = (float*)d_out;
    double* ewl = (double*)(ws + OFF_EW);                      // tb 0..3 (low tree)
    double* ewh = (double*)(ws + OFF_EW) + (size_t)Bn * Ne;    // tb 4..7 (high tree)

    k_init<<<(Bn * Cc * Nn + 255) / 256, 256, 0, stream>>>(
        preds, (float*)(ws + OFF_PROB), (double*)(ws + OFF_ACC));
    k_edgew<<<(Bn * Ne + 255) / 256, 256, 0, stream>>>(lowf, Clow, ewl);
    k_edgew<<<(Bn * Ne + 255) / 256, 256, 0, stream>>>(highf, Chigh, ewh);
    k_mst<<<8, 1024, 0, stream>>>(ws);
    k_bfs<<<8, 256, 0, stream>>>(ws);
    k_dp<<<Bn * NCh, 64, 0, stream>>>(ws, 0, 0);
    k_norm<<<(Bn * Cc * Nn + 255) / 256, 256, 0, stream>>>(ws);
    k_dp<<<Bn * NCh, 64, 0, stream>>>(ws, 1, 1);
    k_loss<<<(Bn * Cc * Nn + 255) / 256, 256, 0, stream>>>(ws, roi);
    k_final<<<1, 64, 0, stream>>>((const double*)(ws + OFF_ACC), out);
}

// Round 6
// 1242.440 us; speedup vs baseline: 1.3044x; 1.2783x over previous
//
#include <hip/hip_runtime.h>
#include <math.h>
#include <stdint.h>
#include <stddef.h>

// TreeEnergyLoss on gfx950 — R6: Euler-tour topology (kills level-sync BFS).
//
//  * k_topo: Euler circuit from dir masks -> ruling-set list ranking (970
//    rulers, stride 19, serial LDS walks + 10 pointer-double rounds) ->
//    descent test gives parent orientation -> +-1 prefix by tour rank gives
//    depth -> counting sort by depth emits the SAME ord/ppos/wgt/lev arrays
//    k_dp consumed before. O(log N) barriers instead of O(D).
//  * k_mst (R5 edge-compaction Boruvka) and k_dp (single-wave) unchanged.
//  * MST matches host Kruskal: exact float64 weights, stable tie-break.

namespace {
constexpr int Bn  = 4, Cc = 21, Hh = 96, Ww = 96;
constexpr int Nn  = Hh * Ww;              // 9216
constexpr int EhE = Hh * (Ww - 1);        // 9120
constexpr int Ne  = EhE + (Hh - 1) * Ww;  // 18240
constexpr int Clow = 3, Chigh = 512;
constexpr int NCh = Cc + 1;               // 22
constexpr int MAXD = 2048;
constexpr int TL  = 2 * (Nn - 1);         // 18430 directed tree edges (tour len)
constexpr int ESL = 18432;                // padded element space
constexpr int SEG = 19;                   // ruler stride (odd!)
constexpr int NR  = (TL + SEG - 1) / SEG; // 970 rulers

// workspace layout (bytes) — all offsets 16B-aligned
constexpr size_t OFF_ACC  = 0;                                        // 2 doubles
constexpr size_t OFF_PROB = 256;                                      // float[B][21][Nn]
constexpr size_t OFF_S1   = OFF_PROB + (size_t)Bn * Cc * Nn * 4;      // float[B][22][Nn]
constexpr size_t OFF_S2   = OFF_S1   + (size_t)Bn * NCh * Nn * 4;     // float[B][22][Nn]
constexpr size_t OFF_EW   = OFF_S2   + (size_t)Bn * NCh * Nn * 4;     // double[8][Ne]
constexpr size_t OFF_ORD  = OFF_EW   + (size_t)8 * Ne * 8;            // int[8][Nn]
constexpr size_t OFF_PPOS = OFF_ORD  + (size_t)8 * Nn * 4;            // ushort[8][Nn]
constexpr size_t OFF_WGT  = OFF_PPOS + (size_t)8 * Nn * 2;            // float[8][Nn]
constexpr size_t OFF_LEV  = OFF_WGT  + (size_t)8 * Nn * 4;            // int[8][MAXD]
constexpr size_t OFF_D    = OFF_LEV  + (size_t)8 * MAXD * 4;          // int[8]
constexpr size_t OFF_DIR  = OFF_D    + 256;                           // int[8][Nn]
constexpr size_t OFF_CBW  = OFF_DIR  + (size_t)8 * Nn * 4;            // ull[8][Nn] | uint[8][ESL]
constexpr size_t OFF_CBE  = OFF_CBW  + (size_t)8 * Nn * 8;            // int[8][Nn] | ushort[8][ESL]
constexpr size_t OFF_OPP  = OFF_CBE  + (size_t)8 * Nn * 4;            // ushort[8][ESL]
constexpr size_t OFF_SGN  = OFF_OPP  + (size_t)8 * ESL * 2;           // int8[8][ESL]
constexpr size_t OFF_PNF  = OFF_SGN  + (size_t)8 * ESL;               // uint[8][Nn]
// edge-list ping/pong for k_mst overlaid on regions dead until k_topo:
constexpr size_t OFF_EL1  = OFF_ORD;                                  // ushort[8][Ne]
constexpr size_t OFF_EL2  = OFF_WGT;                                  // ushort[8][Ne]
} // namespace

// edge id -> endpoints, matching reference concatenate([eh, ev]) ordering
__device__ __forceinline__ void edge_nodes(int e, int& a, int& b) {
    if (e < EhE) { int h = e / (Ww - 1), w = e - h * (Ww - 1); a = h * Ww + w; b = a + 1; }
    else { int e2 = e - EhE; int h = e2 / Ww, w = e2 - h * Ww; a = h * Ww + w; b = a + Ww; }
}
// dirs: 0=E(+1) 1=W(-1) 2=S(+96) 3=N(-96); rev(d)=d^1
__device__ __forceinline__ int dir_delta(int d) {
    return (d == 0) ? 1 : (d == 1) ? -1 : (d == 2) ? Ww : -Ww;
}
__device__ __forceinline__ int edge_of(int u, int d) {
    int h = u / Ww, w = u - h * Ww;
    if (d == 0) return h * (Ww - 1) + w;
    if (d == 1) return h * (Ww - 1) + w - 1;
    if (d == 2) return EhE + u;
    return EhE + u - Ww;
}

__device__ __forceinline__ int uf_find16(unsigned short* uf, int x) {
    while (true) {
        int p = uf[x];
        if (p == x) return x;
        int gp = uf[p];
        if (gp != p) uf[x] = (unsigned short)gp;  // path halving (benign races)
        x = gp;
    }
}

// inclusive block scan of 1024 ints (blockDim.x == 1024); b0/b1 are int[1024]
__device__ __forceinline__ int scan1024_incl(int val, int tid, int* b0, int* b1) {
    b0[tid] = val;
    __syncthreads();
    int* s = b0; int* d = b1;
    for (int off = 1; off < 1024; off <<= 1) {
        int x = s[tid];
        if (tid >= off) x += s[tid - off];
        d[tid] = x;
        __syncthreads();
        int* t = s; s = d; d = t;
    }
    return s[tid];
}

__global__ void k_init(const float* __restrict__ preds, float* __restrict__ prob,
                       double* __restrict__ acc) {
    int idx = blockIdx.x * blockDim.x + threadIdx.x;
    if (idx == 0) { acc[0] = 0.0; acc[1] = 0.0; }
    if (idx >= Bn * Cc * Nn) return;
    prob[idx] = 1.0f / (1.0f + expf(-preds[idx]));
}

// exact float64 edge weights: sequential channel sum matches numpy axis-0 reduce
__global__ void k_edgew(const float* __restrict__ feat, int C, double* __restrict__ ew) {
    int idx = blockIdx.x * blockDim.x + threadIdx.x;
    if (idx >= Bn * Ne) return;
    int b = idx / Ne, e = idx - b * Ne;
    int a, c2; edge_nodes(e, a, c2);
    const float* f = feat + (size_t)b * C * Nn;
    double s = 0.0;
    for (int c = 0; c < C; c++) {
        double d = (double)f[(size_t)c * Nn + a] - (double)f[(size_t)c * Nn + c2];
        s += d * d;
    }
    ew[idx] = s;
}

// Boruvka MST; emits per-node dir bitmask. One block per (tree,batch) tb.
__global__ void __launch_bounds__(1024)
k_mst(char* __restrict__ ws) {
    const int tb = blockIdx.x, tid = threadIdx.x;
    const double* ew = (const double*)(ws + OFF_EW) + (size_t)tb * Ne;
    unsigned long long* cbW = (unsigned long long*)(ws + OFF_CBW) + (size_t)tb * Nn;
    int* cbE  = (int*)(ws + OFF_CBE)  + (size_t)tb * Nn;
    int* dirG = (int*)(ws + OFF_DIR)  + (size_t)tb * Nn;
    unsigned short* elA = (unsigned short*)(ws + OFF_EL1) + (size_t)tb * Ne;
    unsigned short* elB = (unsigned short*)(ws + OFF_EL2) + (size_t)tb * Ne;

    __shared__ unsigned short uf[Nn], comp[Nn], nxt[Nn];
    __shared__ int chgArr[48];
    __shared__ int sLen;

    for (int i = tid; i < Nn; i += 1024) { uf[i] = (unsigned short)i; dirG[i] = 0; }
    if (tid < 48) chgArr[tid] = 0;
    __syncthreads();

    // ---------- round 1: every node picks its min incident edge ----------
    for (int i = tid; i < Nn; i += 1024) {
        int h = i / Ww, w = i - h * Ww;
        unsigned long long bw = ~0ull; int be = 0x7fffffff;
        int cand[4]; int nc = 0;
        if (w < Ww - 1) cand[nc++] = h * (Ww - 1) + w;
        if (w > 0)      cand[nc++] = h * (Ww - 1) + w - 1;
        if (h < Hh - 1) cand[nc++] = EhE + i;
        if (h > 0)      cand[nc++] = EhE + i - Ww;
        for (int k = 0; k < nc; k++) {
            int e = cand[k];
            unsigned long long wb = (unsigned long long)__double_as_longlong(ew[e]);
            if (wb < bw || (wb == bw && e < be)) { bw = wb; be = e; }
        }
        cbE[i] = be;
    }
    __syncthreads();
    for (int i = tid; i < Nn; i += 1024) {
        int e = cbE[i];
        int a, c; edge_nodes(e, a, c);
        nxt[i] = (unsigned short)((a == i) ? c : a);
        int da = (c == a + 1) ? 0 : 2;
        atomicOr(&dirG[a], 1 << da);
        atomicOr(&dirG[c], 1 << (da ^ 1));
    }
    __syncthreads();
    for (int i = tid; i < Nn; i += 1024) {             // break 2-cycles
        int o = nxt[i];
        if (o != i && nxt[o] == i && i < o) nxt[i] = (unsigned short)i;
    }
    __syncthreads();
    {
        int it = 0;
        while (it < 40) {
            bool any = false;
            for (int r = tid; r < Nn; r += 1024) {
                int nr = nxt[r], nnr = nxt[nr];
                if (nr != nnr) { nxt[r] = (unsigned short)nnr; any = true; }
            }
            if (any) chgArr[it] = 1;
            __syncthreads();
            if (!chgArr[it]) break;
            it++;
        }
        for (int r = tid; r < Nn; r += 1024) uf[r] = nxt[r];
        __syncthreads();
    }

    // ---------- rounds >= 2: compacted edge lists ----------
    unsigned short* src = elA;
    unsigned short* dst = elB;
    int srcLen = -1;
    for (int round = 2; round < 20; round++) {
        for (int i = tid; i < Nn; i += 1024)
            comp[i] = (unsigned short)uf_find16(uf, i);
        if (tid == 0) sLen = 0;
        if (tid < 48) chgArr[tid] = 0;
        __syncthreads();
        if (srcLen < 0) {
            for (int e = tid; e < Ne; e += 1024) {
                int a, c; edge_nodes(e, a, c);
                if (comp[a] != comp[c]) dst[atomicAdd(&sLen, 1)] = (unsigned short)e;
            }
        } else {
            for (int k = tid; k < srcLen; k += 1024) {
                int e = src[k];
                int a, c; edge_nodes(e, a, c);
                if (comp[a] != comp[c]) dst[atomicAdd(&sLen, 1)] = (unsigned short)e;
            }
        }
        __syncthreads();
        int len = sLen;
        if (len == 0) break;
        for (int i = tid; i < Nn; i += 1024) { cbW[i] = ~0ull; cbE[i] = 0x7fffffff; }
        __syncthreads();
        for (int k = tid; k < len; k += 1024) {
            int e = dst[k];
            int a, c; edge_nodes(e, a, c);
            unsigned long long wb = (unsigned long long)__double_as_longlong(ew[e]);
            atomicMin(&cbW[comp[a]], wb); atomicMin(&cbW[comp[c]], wb);
        }
        __syncthreads();
        for (int k = tid; k < len; k += 1024) {
            int e = dst[k];
            int a, c; edge_nodes(e, a, c);
            unsigned long long wb = (unsigned long long)__double_as_longlong(ew[e]);
            if (wb == cbW[comp[a]]) atomicMin(&cbE[comp[a]], e);
            if (wb == cbW[comp[c]]) atomicMin(&cbE[comp[c]], e);
        }
        __syncthreads();
        for (int r = tid; r < Nn; r += 1024) {
            if (comp[r] == r) {
                int e = cbE[r];
                if (e != 0x7fffffff) {
                    int a, c; edge_nodes(e, a, c);
                    nxt[r] = (unsigned short)((comp[a] == r) ? comp[c] : comp[a]);
                    int da = (c == a + 1) ? 0 : 2;
                    atomicOr(&dirG[a], 1 << da);
                    atomicOr(&dirG[c], 1 << (da ^ 1));
                } else nxt[r] = (unsigned short)r;
            }
        }
        __syncthreads();
        for (int r = tid; r < Nn; r += 1024) {
            if (comp[r] == r) {
                int o = nxt[r];
                if (o != r && nxt[o] == r && r < o) nxt[r] = (unsigned short)r;
            }
        }
        __syncthreads();
        int it = 0;
        while (it < 40) {
            bool any = false;
            for (int r = tid; r < Nn; r += 1024) {
                if (comp[r] == r) {
                    int nr = nxt[r], nnr = nxt[nr];
                    if (nr != nnr) { nxt[r] = (unsigned short)nnr; any = true; }
                }
            }
            if (any) chgArr[it] = 1;
            __syncthreads();
            if (!chgArr[it]) break;
            it++;
        }
        for (int r = tid; r < Nn; r += 1024)
            if (comp[r] == r) uf[r] = nxt[r];
        __syncthreads();
        unsigned short* t = src; src = dst; dst = t;
        srcLen = len;
    }
}

// Euler-tour topology: orientation + depth + level-compacted order, O(log N).
__global__ void __launch_bounds__(1024)
k_topo(char* __restrict__ ws) {
    const int tb = blockIdx.x, tid = threadIdx.x;
    const int tree = tb >> 2;
    const double* ew  = (const double*)(ws + OFF_EW) + (size_t)tb * Ne;
    const int*  dirG  = (const int*)(ws + OFF_DIR) + (size_t)tb * Nn;
    unsigned int*   elemSegG = (unsigned int*)(ws + OFF_CBW) + (size_t)tb * ESL;
    unsigned short* ownG     = (unsigned short*)(ws + OFF_CBE) + (size_t)tb * ESL;
    unsigned short* oppG     = (unsigned short*)(ws + OFF_OPP) + (size_t)tb * ESL;
    signed char*    sgnG     = (signed char*)(ws + OFF_SGN) + (size_t)tb * ESL;
    unsigned int*   pinfoG   = (unsigned int*)(ws + OFF_PNF) + (size_t)tb * Nn;
    int*            ordG  = (int*)(ws + OFF_ORD)  + (size_t)tb * Nn;
    unsigned short* pposG = (unsigned short*)(ws + OFF_PPOS) + (size_t)tb * Nn;
    float*          wgtG  = (float*)(ws + OFF_WGT) + (size_t)tb * Nn;
    int*            levG  = (int*)(ws + OFF_LEV)  + (size_t)tb * MAXD;
    int*            dG    = (int*)(ws + OFF_D);
    const float inv_sigma = tree ? 1.0f : 50.0f;

    __shared__ char SB[64512];           // A:36864 | B:18432 | C:9216
    char* Areg = SB;
    char* Breg = SB + 36864;
    char* Creg = SB + 55296;
    __shared__ int sMax;

    // ---- P0: masks -> LDS; degree prefix sums ----
    unsigned short* degOff = (unsigned short*)Breg;
    unsigned char*  nbS    = (unsigned char*)Creg;
    for (int i = tid; i < Nn; i += 1024) nbS[i] = (unsigned char)dirG[i];
    if (tid == 0) sMax = 0;
    __syncthreads();
    {
        int base9 = tid * 9;
        int loc[9]; int s = 0;
        #pragma unroll
        for (int k = 0; k < 9; k++) { loc[k] = s; s += __popc(nbS[base9 + k]); }
        int incl = scan1024_incl(s, tid, (int*)Areg, (int*)(Areg + 4096));
        int eb = incl - s;
        #pragma unroll
        for (int k = 0; k < 9; k++) degOff[base9 + k] = (unsigned short)(eb + loc[k]);
    }
    __syncthreads();

    // ---- P1: build Euler successor + owner + opposite ----
    unsigned short* nxtS = (unsigned short*)Areg;
    for (int u = tid; u < Nn; u += 1024) {
        int m = nbS[u]; int base = degOff[u]; int k = 0;
        #pragma unroll
        for (int d = 0; d < 4; d++) {
            if (m & (1 << d)) {
                int v = u + dir_delta(d);
                int mv = nbS[v]; int rd = d ^ 1;
                int pv = __popc(mv & ((1 << rd) - 1));
                int dv = __popc(mv);
                int nx = pv + 1; if (nx == dv) nx = 0;
                int j = base + k;
                nxtS[j] = (unsigned short)(degOff[v] + nx);
                ownG[j] = (unsigned short)((u << 2) | d);
                oppG[j] = (unsigned short)(degOff[v] + pv);
                k++;
            }
        }
    }
    __syncthreads();

    // ---- P2: ruling-set walks (segment = arc between rulers) ----
    int myNr = 0, myLen = 0;
    if (tid < NR) {
        int x = tid * SEG, off = 0;
        for (int g = 0; g < 4096; g++) {
            elemSegG[x] = ((unsigned)tid << 11) | (unsigned)off;
            int y = nxtS[x];
            if (y % SEG == 0) { myNr = y / SEG; myLen = off + 1; break; }
            x = y; off++;
        }
    }
    __syncthreads();

    // ---- P3: rank rulers by pointer doubling (terminal at ruler 0) ----
    unsigned short* cn = (unsigned short*)Creg;
    unsigned short* cd = (unsigned short*)(Creg + 2048);
    unsigned short* nn2 = (unsigned short*)(Creg + 4096);
    unsigned short* nd2 = (unsigned short*)(Creg + 6144);
    if (tid == 0)      { cn[0] = 0; cd[0] = 0; }
    else if (tid < NR) { cn[tid] = (unsigned short)myNr; cd[tid] = (unsigned short)myLen; }
    else               { cn[tid] = (unsigned short)tid; cd[tid] = 0; }
    __syncthreads();
    for (int r = 0; r < 10; r++) {
        int c = cn[tid];
        int dv = cd[tid] + cd[c];
        int n2 = cn[c];
        nn2[tid] = (unsigned short)n2; nd2[tid] = (unsigned short)dv;
        __syncthreads();
        unsigned short* t;
        t = cn; cn = nn2; nn2 = t;
        t = cd; cd = nd2; nd2 = t;
    }
    unsigned short* rb = nn2;  // dead ping buffer hosts rank bases
    rb[tid] = (tid == 0) ? 0 : (unsigned short)(TL - cd[tid]);
    __syncthreads();

    // ---- P4: per-element rank ----
    unsigned short* rankS = (unsigned short*)Areg;  // overlays nxtS (dead)
    for (int e = tid; e < TL; e += 1024) {
        unsigned int pk = elemSegG[e];
        rankS[e] = (unsigned short)(rb[pk >> 11] + (pk & 2047));
    }
    __syncthreads();

    // ---- P5: descent test -> sign by rank, parent info per node ----
    for (int e = tid; e < TL; e += 1024) {
        int own = ownG[e];
        int u = own >> 2, d = own & 3;
        int re = rankS[e];
        int ro = rankS[oppG[e]];
        bool desc = re < ro;
        sgnG[re] = desc ? 1 : -1;
        if (desc) {
            int v = u + dir_delta(d);
            pinfoG[v] = ((unsigned)(d ^ 1) << 15) | (unsigned)re;
        }
    }
    __syncthreads();

    // ---- P6: inclusive +-1 scan over tour ranks (depth field) ----
    short* scanS = (short*)Areg;   // overlays rankS (dead)
    {
        int base = tid * 18;
        int n = TL - base; if (n > 18) n = 18; if (n < 0) n = 0;
        int s = 0;
        for (int k = 0; k < n; k++) { s += sgnG[base + k]; scanS[base + k] = (short)s; }
        int incl = scan1024_incl(s, tid, (int*)Creg, (int*)(Creg + 4096));
        int eb = incl - s;
        for (int k = 0; k < n; k++) scanS[base + k] = (short)(scanS[base + k] + eb);
    }
    __syncthreads();

    // ---- P7: depth per node ----
    unsigned short* depthS = (unsigned short*)Breg;  // overlays degOff (dead)
    for (int v = tid; v < Nn; v += 1024) {
        int dep = 0;
        if (v != 0) {
            int rin = (int)(pinfoG[v] & 0x7FFF);
            dep = scanS[rin];
            if (dep > MAXD - 1) dep = MAXD - 1;
        }
        depthS[v] = (unsigned short)dep;
        atomicMax(&sMax, dep);
    }
    __syncthreads();
    const int D = sMax + 1;

    // ---- P8: counting sort by depth ----
    int* hist = (int*)Creg;                          // int[2048]
    for (int k = tid; k < 2048; k += 1024) hist[k] = 0;
    __syncthreads();
    for (int v = tid; v < Nn; v += 1024) atomicAdd(&hist[depthS[v]], 1);
    __syncthreads();
    int* levOff = (int*)(Areg + 8192);               // int[2048]
    {
        int h0 = hist[2 * tid], h1 = hist[2 * tid + 1];
        int partial = h0 + h1;
        int incl = scan1024_incl(partial, tid, (int*)Areg, (int*)(Areg + 4096));
        int eb = incl - partial;
        levOff[2 * tid] = eb;
        levOff[2 * tid + 1] = eb + h0;
    }
    __syncthreads();
    for (int d = tid; d <= D && d < 2048; d += 1024) levG[d] = levOff[d];
    for (int k = tid; k < 2048; k += 1024) hist[k] = 0;   // reuse as counters
    __syncthreads();
    unsigned short* posOfS = (unsigned short*)(Areg + 16384);
    for (int v = tid; v < Nn; v += 1024) {
        int dep = depthS[v];
        int pos = levOff[dep] + atomicAdd(&hist[dep], 1);
        posOfS[v] = (unsigned short)pos;
        ordG[pos] = v;
    }
    __syncthreads();

    // ---- P9: ppos + filter weights ----
    for (int v = tid; v < Nn; v += 1024) {
        int pos = posOfS[v];
        if (v == 0) { pposG[pos] = 0; wgtG[pos] = 0.0f; }
        else {
            unsigned int pi = pinfoG[v];
            int rd = (int)(pi >> 15);
            int p = v + dir_delta(rd);
            pposG[pos] = posOfS[p];
            wgtG[pos] = expf(-(float)ew[edge_of(v, rd)] * inv_sigma);
        }
    }
    if (tid == 0) dG[tb] = D;
}

// Single-wave two-pass tree DP for one (batch, channel); wgt prefetched.
__global__ void __launch_bounds__(64)
k_dp(char* __restrict__ ws, int tree, int inMode) {
    const int bc = blockIdx.x;
    const int b = bc / NCh, c = bc % NCh;
    const int tb = tree * Bn + b;
    const int lane = threadIdx.x;
    const int*            ordG  = (const int*)(ws + OFF_ORD)  + (size_t)tb * Nn;
    const unsigned short* pposG = (const unsigned short*)(ws + OFF_PPOS) + (size_t)tb * Nn;
    const float*          wgtG  = (const float*)(ws + OFF_WGT) + (size_t)tb * Nn;
    const int*            levG  = (const int*)(ws + OFF_LEV)  + (size_t)tb * MAXD;
    const int D = ((const int*)(ws + OFF_D))[tb];
    const float* src = (inMode == 0)
        ? (const float*)(ws + OFF_PROB) + ((size_t)b * Cc + c) * Nn
        : (const float*)(ws + OFF_S1)   + ((size_t)b * NCh + c) * Nn;
    float* dst = (float*)(ws + (tree ? OFF_S2 : OFF_S1)) + ((size_t)b * NCh + c) * Nn;

    __shared__ alignas(16) float Al[Nn];
    __shared__ alignas(16) unsigned short pposS[Nn];
    __shared__ unsigned short levS[MAXD];

    {
        const uint4* pg4 = (const uint4*)pposG;
        uint4* ps4 = (uint4*)pposS;
        for (int k = lane; k < Nn / 8; k += 64) ps4[k] = pg4[k];
    }
    for (int d = lane; d <= D; d += 64) levS[d] = (unsigned short)levG[d];
    if (c == Cc) { for (int i = lane; i < Nn; i += 64) Al[i] = 1.0f; }
    else         { for (int i = lane; i < Nn; i += 64) Al[i] = src[ordG[i]]; }
    __syncthreads();

    // up: children before parents (ds_add_f32, no return — off the chain)
    {
        int d = D - 1;
        int s0 = levS[d], s1 = levS[d + 1];
        float wq = (s0 + lane < s1) ? wgtG[s0 + lane] : 0.0f;
        for (; d >= 1; d--) {
            s0 = levS[d]; s1 = levS[d + 1];
            float wq_next = 0.0f;
            if (d > 1) {
                int p0 = levS[d - 1];
                if (p0 + lane < s0) wq_next = wgtG[p0 + lane];
            }
            int i = s0 + lane;
            if (i < s1) atomicAdd(&Al[pposS[i]], wq * Al[i]);
            for (i = s0 + lane + 64; i < s1; i += 64)
                atomicAdd(&Al[pposS[i]], wgtG[i] * Al[i]);
            __syncthreads();
            wq = wq_next;
        }
    }
    // down: parents before children
    if (D > 1) {
        int s0 = levS[1], s1 = levS[2 <= D ? 2 : 1];
        float wq = (s0 + lane < s1) ? wgtG[s0 + lane] : 0.0f;
        for (int d = 1; d < D; d++) {
            s0 = levS[d]; s1 = levS[d + 1];
            float wq_next = 0.0f;
            if (d + 1 < D) {
                int n0 = levS[d + 1], n1 = levS[d + 2];
                if (n0 + lane < n1) wq_next = wgtG[n0 + lane];
            }
            int i = s0 + lane;
            if (i < s1) { float w = wq, a = Al[i]; Al[i] = a + w * (Al[pposS[i]] - w * a); }
            for (i = s0 + lane + 64; i < s1; i += 64) {
                float w = wgtG[i], a = Al[i];
                Al[i] = a + w * (Al[pposS[i]] - w * a);
            }
            __syncthreads();
            wq = wq_next;
        }
    }
    for (int i = lane; i < Nn; i += 64) dst[ordG[i]] = Al[i];
}

// normalize S1 channels by norm channel (flat; removes work from dp2 gather)
__global__ void k_norm(char* __restrict__ ws) {
    int idx = blockIdx.x * 256 + threadIdx.x;
    if (idx >= Bn * Cc * Nn) return;
    int b = idx / (Cc * Nn), rem = idx - b * (Cc * Nn);
    int c = rem / Nn, n = rem - c * Nn;
    float* S1 = (float*)(ws + OFF_S1);
    S1[((size_t)b * NCh + c) * Nn + n] /= S1[((size_t)b * NCh + Cc) * Nn + n];
}

__global__ void k_loss(char* __restrict__ ws, const float* __restrict__ roi) {
    const int tid = threadIdx.x;
    int idx = blockIdx.x * 256 + tid;
    const float* prob = (const float*)(ws + OFF_PROB);
    const float* S2   = (const float*)(ws + OFF_S2);
    double* acc = (double*)(ws + OFF_ACC);
    double ls = 0.0, cnt = 0.0;
    if (idx < Bn * Cc * Nn) {
        int b = idx / (Cc * Nn);
        int rem = idx - b * (Cc * Nn);
        int c = rem / Nn, n = rem - c * Nn;
        int h = n / Ww, w2 = n - h * Ww;
        float r = roi[(size_t)b * (2 * Hh) * (2 * Ww) + (size_t)(2 * h) * (2 * Ww) + 2 * w2];
        float as = S2[((size_t)b * NCh + c) * Nn + n] / S2[((size_t)b * NCh + Cc) * Nn + n];
        float pp = prob[((size_t)b * Cc + c) * Nn + n];
        ls = (double)(r * fabsf(pp - as));
        if (c == 0) cnt = (double)r;
    }
    __shared__ double sl[256], sc2[256];
    sl[tid] = ls; sc2[tid] = cnt;
    __syncthreads();
    for (int s = 128; s > 0; s >>= 1) {
        if (tid < s) { sl[tid] += sl[tid + s]; sc2[tid] += sc2[tid + s]; }
        __syncthreads();
    }
    if (tid == 0) { atomicAdd(acc, sl[0]); atomicAdd(acc + 1, sc2[0]); }
}

__global__ void k_final(const double* __restrict__ acc, float* __restrict__ out) {
    if (blockIdx.x == 0 && threadIdx.x == 0)
        out[0] = (acc[1] > 0.0) ? (float)(acc[0] / acc[1]) : 0.0f;
}

extern "C" void kernel_launch(void* const* d_in, const int* in_sizes, int n_in,
                              void* d_out, int out_size, void* d_ws, size_t ws_size,
                              hipStream_t stream) {
    const float* preds = (const float*)d_in[0];
    const float* lowf  = (const float*)d_in[1];
    const float* highf = (const float*)d_in[2];
    const float* roi   = (const float*)d_in[3];
    char* ws = (char*)d_ws;
    float* out = (float*)d_out;
    double* ewl = (double*)(ws + OFF_EW);                      // tb 0..3 (low tree)
    double* ewh = (double*)(ws + OFF_EW) + (size_t)Bn * Ne;    // tb 4..7 (high tree)

    k_init<<<(Bn * Cc * Nn + 255) / 256, 256, 0, stream>>>(
        preds, (float*)(ws + OFF_PROB), (double*)(ws + OFF_ACC));
    k_edgew<<<(Bn * Ne + 255) / 256, 256, 0, stream>>>(lowf, Clow, ewl);
    k_edgew<<<(Bn * Ne + 255) / 256, 256, 0, stream>>>(highf, Chigh, ewh);
    k_mst<<<8, 1024, 0, stream>>>(ws);
    k_topo<<<8, 1024, 0, stream>>>(ws);
    k_dp<<<Bn * NCh, 64, 0, stream>>>(ws, 0, 0);
    k_norm<<<(Bn * Cc * Nn + 255) / 256, 256, 0, stream>>>(ws);
    k_dp<<<Bn * NCh, 64, 0, stream>>>(ws, 1, 1);
    k_loss<<<(Bn * Cc * Nn + 255) / 256, 256, 0, stream>>>(ws, roi);
    k_final<<<1, 64, 0, stream>>>((const double*)(ws + OFF_ACC), out);
}

// Round 7
// 1168.861 us; speedup vs baseline: 1.3865x; 1.0629x over previous
//
#include <hip/hip_runtime.h>
#include <math.h>
#include <stdint.h>
#include <stddef.h>

// TreeEnergyLoss on gfx950 — R7: centroid rooting via Euler-rank rotation
// (cuts tree height ~1.5x => both DP dispatches shorten), plus wave-aggregated
// compaction in Boruvka.
//
//  * k_topo: ranks computed once; 4 scan rounds (root 0 -> u=farthest ->
//    v=farthest(u) [diam] -> center). Re-rooting = rank rotation; signs and
//    +-1 depth scan recomputed per root as flat passes. Final round emits
//    parent info + level-compacted ord/ppos/wgt/lev for the center root.
//  * k_mst: compaction counter updated once per wave (ballot+popc), not per
//    thread. Min-edge selection remains exact (w_f64, edge idx) total order.
//  * Filter is root-independent => center root is mathematically identical.

namespace {
constexpr int Bn  = 4, Cc = 21, Hh = 96, Ww = 96;
constexpr int Nn  = Hh * Ww;              // 9216
constexpr int EhE = Hh * (Ww - 1);        // 9120
constexpr int Ne  = EhE + (Hh - 1) * Ww;  // 18240
constexpr int Clow = 3, Chigh = 512;
constexpr int NCh = Cc + 1;               // 22
constexpr int MAXD = 2048;
constexpr int TL  = 2 * (Nn - 1);         // 18430 arcs
constexpr int ESL = 18432;
constexpr int SEG = 19;                   // ruler stride (odd)
constexpr int NR  = (TL + SEG - 1) / SEG; // 970 rulers

// workspace layout (bytes) — 16B-aligned
constexpr size_t OFF_ACC  = 0;                                        // 2 doubles
constexpr size_t OFF_PROB = 256;                                      // float[B][21][Nn]
constexpr size_t OFF_S1   = OFF_PROB + (size_t)Bn * Cc * Nn * 4;      // float[B][22][Nn]
constexpr size_t OFF_S2   = OFF_S1   + (size_t)Bn * NCh * Nn * 4;     // float[B][22][Nn]
constexpr size_t OFF_EW   = OFF_S2   + (size_t)Bn * NCh * Nn * 4;     // double[8][Ne]
constexpr size_t OFF_ORD  = OFF_EW   + (size_t)8 * Ne * 8;            // int[8][Nn]
constexpr size_t OFF_PPOS = OFF_ORD  + (size_t)8 * Nn * 4;            // ushort[8][Nn]
constexpr size_t OFF_WGT  = OFF_PPOS + (size_t)8 * Nn * 2;            // float[8][Nn]
constexpr size_t OFF_LEV  = OFF_WGT  + (size_t)8 * Nn * 4;            // int[8][MAXD]
constexpr size_t OFF_D    = OFF_LEV  + (size_t)8 * MAXD * 4;          // int[8]
constexpr size_t OFF_DIR  = OFF_D    + 256;                           // int[8][Nn]
constexpr size_t OFF_CBW  = OFF_DIR  + (size_t)8 * Nn * 4;            // ull[8][Nn] | uint[8][ESL]
constexpr size_t OFF_CBE  = OFF_CBW  + (size_t)8 * Nn * 8;            // int[8][Nn] | ushort[8][ESL]
constexpr size_t OFF_OPP  = OFF_CBE  + (size_t)8 * Nn * 4;            // ushort[8][ESL]
constexpr size_t OFF_SGN  = OFF_OPP  + (size_t)8 * ESL * 2;           // int8[8][ESL]
constexpr size_t OFF_PNF  = OFF_SGN  + (size_t)8 * ESL;               // uint[8][Nn]
constexpr size_t OFF_RNK  = OFF_PNF  + (size_t)8 * Nn * 4;            // ushort[8][ESL]
// k_mst edge-list ping/pong overlaid on regions dead until k_topo:
constexpr size_t OFF_EL1  = OFF_ORD;                                  // ushort[8][Ne]
constexpr size_t OFF_EL2  = OFF_WGT;                                  // ushort[8][Ne]
} // namespace

__device__ __forceinline__ void edge_nodes(int e, int& a, int& b) {
    if (e < EhE) { int h = e / (Ww - 1), w = e - h * (Ww - 1); a = h * Ww + w; b = a + 1; }
    else { int e2 = e - EhE; int h = e2 / Ww, w = e2 - h * Ww; a = h * Ww + w; b = a + Ww; }
}
// dirs: 0=E(+1) 1=W(-1) 2=S(+96) 3=N(-96); rev(d)=d^1
__device__ __forceinline__ int dir_delta(int d) {
    return (d == 0) ? 1 : (d == 1) ? -1 : (d == 2) ? Ww : -Ww;
}
__device__ __forceinline__ int edge_of(int u, int d) {
    int h = u / Ww, w = u - h * Ww;
    if (d == 0) return h * (Ww - 1) + w;
    if (d == 1) return h * (Ww - 1) + w - 1;
    if (d == 2) return EhE + u;
    return EhE + u - Ww;
}

__device__ __forceinline__ int uf_find16(unsigned short* uf, int x) {
    while (true) {
        int p = uf[x];
        if (p == x) return x;
        int gp = uf[p];
        if (gp != p) uf[x] = (unsigned short)gp;
        x = gp;
    }
}

// wave-aggregated compaction push (1 LDS atomic per wave instead of 64)
__device__ __forceinline__ void compact_push(bool keep, int val, int* cnt,
                                             unsigned short* out, int lane) {
    unsigned long long m = __ballot(keep ? 1 : 0);
    if (m == 0ull) return;
    int leader = __ffsll((unsigned long long)m) - 1;
    int base = 0;
    if (lane == leader) base = atomicAdd(cnt, __popcll(m));
    base = __shfl(base, leader, 64);
    if (keep) {
        unsigned long long lower = m & ((1ull << lane) - 1ull);
        out[base + __popcll(lower)] = (unsigned short)val;
    }
}

// inclusive block scan of 1024 ints; b0/b1 are int[1024]
__device__ __forceinline__ int scan1024_incl(int val, int tid, int* b0, int* b1) {
    b0[tid] = val;
    __syncthreads();
    int* s = b0; int* d = b1;
    for (int off = 1; off < 1024; off <<= 1) {
        int x = s[tid];
        if (tid >= off) x += s[tid - off];
        d[tid] = x;
        __syncthreads();
        int* t = s; s = d; d = t;
    }
    return s[tid];
}

__global__ void k_init(const float* __restrict__ preds, float* __restrict__ prob,
                       double* __restrict__ acc) {
    int idx = blockIdx.x * blockDim.x + threadIdx.x;
    if (idx == 0) { acc[0] = 0.0; acc[1] = 0.0; }
    if (idx >= Bn * Cc * Nn) return;
    prob[idx] = 1.0f / (1.0f + expf(-preds[idx]));
}

// exact float64 edge weights: sequential channel sum matches numpy axis-0 reduce
__global__ void k_edgew(const float* __restrict__ feat, int C, double* __restrict__ ew) {
    int idx = blockIdx.x * blockDim.x + threadIdx.x;
    if (idx >= Bn * Ne) return;
    int b = idx / Ne, e = idx - b * Ne;
    int a, c2; edge_nodes(e, a, c2);
    const float* f = feat + (size_t)b * C * Nn;
    double s = 0.0;
    for (int c = 0; c < C; c++) {
        double d = (double)f[(size_t)c * Nn + a] - (double)f[(size_t)c * Nn + c2];
        s += d * d;
    }
    ew[idx] = s;
}

// Boruvka MST; emits per-node dir bitmask. One block per (tree,batch) tb.
__global__ void __launch_bounds__(1024)
k_mst(char* __restrict__ ws) {
    const int tb = blockIdx.x, tid = threadIdx.x;
    const int lane = tid & 63;
    const double* ew = (const double*)(ws + OFF_EW) + (size_t)tb * Ne;
    unsigned long long* cbW = (unsigned long long*)(ws + OFF_CBW) + (size_t)tb * Nn;
    int* cbE  = (int*)(ws + OFF_CBE)  + (size_t)tb * Nn;
    int* dirG = (int*)(ws + OFF_DIR)  + (size_t)tb * Nn;
    unsigned short* elA = (unsigned short*)(ws + OFF_EL1) + (size_t)tb * Ne;
    unsigned short* elB = (unsigned short*)(ws + OFF_EL2) + (size_t)tb * Ne;

    __shared__ unsigned short uf[Nn], comp[Nn], nxt[Nn];
    __shared__ int chgArr[48];
    __shared__ int sLen;

    for (int i = tid; i < Nn; i += 1024) { uf[i] = (unsigned short)i; dirG[i] = 0; }
    if (tid < 48) chgArr[tid] = 0;
    __syncthreads();

    // ---------- round 1: every node picks its min incident edge ----------
    for (int i = tid; i < Nn; i += 1024) {
        int h = i / Ww, w = i - h * Ww;
        unsigned long long bw = ~0ull; int be = 0x7fffffff;
        int cand[4]; int nc = 0;
        if (w < Ww - 1) cand[nc++] = h * (Ww - 1) + w;
        if (w > 0)      cand[nc++] = h * (Ww - 1) + w - 1;
        if (h < Hh - 1) cand[nc++] = EhE + i;
        if (h > 0)      cand[nc++] = EhE + i - Ww;
        for (int k = 0; k < nc; k++) {
            int e = cand[k];
            unsigned long long wb = (unsigned long long)__double_as_longlong(ew[e]);
            if (wb < bw || (wb == bw && e < be)) { bw = wb; be = e; }
        }
        cbE[i] = be;
    }
    __syncthreads();
    for (int i = tid; i < Nn; i += 1024) {
        int e = cbE[i];
        int a, c; edge_nodes(e, a, c);
        nxt[i] = (unsigned short)((a == i) ? c : a);
        int da = (c == a + 1) ? 0 : 2;
        atomicOr(&dirG[a], 1 << da);
        atomicOr(&dirG[c], 1 << (da ^ 1));
    }
    __syncthreads();
    for (int i = tid; i < Nn; i += 1024) {             // break 2-cycles
        int o = nxt[i];
        if (o != i && nxt[o] == i && i < o) nxt[i] = (unsigned short)i;
    }
    __syncthreads();
    {
        int it = 0;
        while (it < 40) {
            bool any = false;
            for (int r = tid; r < Nn; r += 1024) {
                int nr = nxt[r], nnr = nxt[nr];
                if (nr != nnr) { nxt[r] = (unsigned short)nnr; any = true; }
            }
            if (any) chgArr[it] = 1;
            __syncthreads();
            if (!chgArr[it]) break;
            it++;
        }
        for (int r = tid; r < Nn; r += 1024) uf[r] = nxt[r];
        __syncthreads();
    }

    // ---------- rounds >= 2: compacted edge lists ----------
    unsigned short* src = elA;
    unsigned short* dst = elB;
    int srcLen = -1;
    for (int round = 2; round < 20; round++) {
        for (int i = tid; i < Nn; i += 1024)
            comp[i] = (unsigned short)uf_find16(uf, i);
        if (tid == 0) sLen = 0;
        if (tid < 48) chgArr[tid] = 0;
        __syncthreads();
        if (srcLen < 0) {
            for (int e = tid; e < Ne; e += 1024) {
                int a, c; edge_nodes(e, a, c);
                compact_push(comp[a] != comp[c], e, &sLen, dst, lane);
            }
        } else {
            for (int k = tid; k < srcLen; k += 1024) {
                int e = src[k];
                int a, c; edge_nodes(e, a, c);
                compact_push(comp[a] != comp[c], e, &sLen, dst, lane);
            }
        }
        __syncthreads();
        int len = sLen;
        if (len == 0) break;
        for (int i = tid; i < Nn; i += 1024) { cbW[i] = ~0ull; cbE[i] = 0x7fffffff; }
        __syncthreads();
        for (int k = tid; k < len; k += 1024) {          // pass 1: min weight
            int e = dst[k];
            int a, c; edge_nodes(e, a, c);
            unsigned long long wb = (unsigned long long)__double_as_longlong(ew[e]);
            atomicMin(&cbW[comp[a]], wb); atomicMin(&cbW[comp[c]], wb);
        }
        __syncthreads();
        for (int k = tid; k < len; k += 1024) {          // pass 2: min edge idx
            int e = dst[k];
            int a, c; edge_nodes(e, a, c);
            unsigned long long wb = (unsigned long long)__double_as_longlong(ew[e]);
            if (wb == cbW[comp[a]]) atomicMin(&cbE[comp[a]], e);
            if (wb == cbW[comp[c]]) atomicMin(&cbE[comp[c]], e);
        }
        __syncthreads();
        for (int r = tid; r < Nn; r += 1024) {
            if (comp[r] == r) {
                int e = cbE[r];
                if (e != 0x7fffffff) {
                    int a, c; edge_nodes(e, a, c);
                    nxt[r] = (unsigned short)((comp[a] == r) ? comp[c] : comp[a]);
                    int da = (c == a + 1) ? 0 : 2;
                    atomicOr(&dirG[a], 1 << da);
                    atomicOr(&dirG[c], 1 << (da ^ 1));
                } else nxt[r] = (unsigned short)r;
            }
        }
        __syncthreads();
        for (int r = tid; r < Nn; r += 1024) {
            if (comp[r] == r) {
                int o = nxt[r];
                if (o != r && nxt[o] == r && r < o) nxt[r] = (unsigned short)r;
            }
        }
        __syncthreads();
        int it = 0;
        while (it < 40) {
            bool any = false;
            for (int r = tid; r < Nn; r += 1024) {
                if (comp[r] == r) {
                    int nr = nxt[r], nnr = nxt[nr];
                    if (nr != nnr) { nxt[r] = (unsigned short)nnr; any = true; }
                }
            }
            if (any) chgArr[it] = 1;
            __syncthreads();
            if (!chgArr[it]) break;
            it++;
        }
        for (int r = tid; r < Nn; r += 1024)
            if (comp[r] == r) uf[r] = nxt[r];
        __syncthreads();
        unsigned short* t = src; src = dst; dst = t;
        srcLen = len;
    }
}

// Euler-tour topology with CENTER rooting. Ranks once; 4 rotation-scan rounds.
__global__ void __launch_bounds__(1024)
k_topo(char* __restrict__ ws) {
    const int tb = blockIdx.x, tid = threadIdx.x;
    const int tree = tb >> 2;
    const double* ew  = (const double*)(ws + OFF_EW) + (size_t)tb * Ne;
    const int*  dirG  = (const int*)(ws + OFF_DIR) + (size_t)tb * Nn;
    unsigned int*   elemSegG = (unsigned int*)(ws + OFF_CBW) + (size_t)tb * ESL;
    unsigned short* ownG     = (unsigned short*)(ws + OFF_CBE) + (size_t)tb * ESL;
    unsigned short* oppG     = (unsigned short*)(ws + OFF_OPP) + (size_t)tb * ESL;
    signed char*    sgnG     = (signed char*)(ws + OFF_SGN) + (size_t)tb * ESL;
    unsigned int*   pinfoG   = (unsigned int*)(ws + OFF_PNF) + (size_t)tb * Nn;
    unsigned short* rank0G   = (unsigned short*)(ws + OFF_RNK) + (size_t)tb * ESL;
    int*            ordG  = (int*)(ws + OFF_ORD)  + (size_t)tb * Nn;
    unsigned short* pposG = (unsigned short*)(ws + OFF_PPOS) + (size_t)tb * Nn;
    float*          wgtG  = (float*)(ws + OFF_WGT) + (size_t)tb * Nn;
    int*            levG  = (int*)(ws + OFF_LEV)  + (size_t)tb * MAXD;
    int*            dG    = (int*)(ws + OFF_D);
    const float inv_sigma = tree ? 1.0f : 50.0f;

    __shared__ char SB[64512];           // R0:36864 | R1:18432 | R2:9216
    char* R0 = SB;
    char* R1 = SB + 36864;
    char* R2 = SB + 55296;
    __shared__ int sPack, sCenter, sInt, sMax;

    // ---- P0: masks -> LDS; degree prefix sums ----
    unsigned short* degOff = (unsigned short*)R1;
    unsigned char*  nbS    = (unsigned char*)R2;
    for (int i = tid; i < Nn; i += 1024) nbS[i] = (unsigned char)dirG[i];
    __syncthreads();
    {
        int base9 = tid * 9;
        int loc[9]; int s = 0;
        #pragma unroll
        for (int k = 0; k < 9; k++) { loc[k] = s; s += __popc(nbS[base9 + k]); }
        int incl = scan1024_incl(s, tid, (int*)R0, (int*)(R0 + 4096));
        int eb = incl - s;
        #pragma unroll
        for (int k = 0; k < 9; k++) degOff[base9 + k] = (unsigned short)(eb + loc[k]);
    }
    __syncthreads();

    // ---- P1: Euler successor + owner + opposite ----
    unsigned short* nxtS = (unsigned short*)R0;
    for (int u = tid; u < Nn; u += 1024) {
        int m = nbS[u]; int base = degOff[u]; int k = 0;
        #pragma unroll
        for (int d = 0; d < 4; d++) {
            if (m & (1 << d)) {
                int v = u + dir_delta(d);
                int mv = nbS[v]; int rd = d ^ 1;
                int pv = __popc(mv & ((1 << rd) - 1));
                int dv = __popc(mv);
                int nx = pv + 1; if (nx == dv) nx = 0;
                int j = base + k;
                nxtS[j] = (unsigned short)(degOff[v] + nx);
                ownG[j] = (unsigned short)((u << 2) | d);
                oppG[j] = (unsigned short)(degOff[v] + pv);
                k++;
            }
        }
    }
    __syncthreads();

    // ---- P2: ruling-set walks ----
    int myNr = 0, myLen = 0;
    if (tid < NR) {
        int x = tid * SEG, off = 0;
        for (int g = 0; g < 4096; g++) {
            elemSegG[x] = ((unsigned)tid << 11) | (unsigned)off;
            int y = nxtS[x];
            if (y % SEG == 0) { myNr = y / SEG; myLen = off + 1; break; }
            x = y; off++;
        }
    }
    __syncthreads();

    // ---- P3: ruler pointer doubling (in R2; nbS dead) ----
    unsigned short* cn  = (unsigned short*)R2;
    unsigned short* cd  = (unsigned short*)(R2 + 2048);
    unsigned short* nn2 = (unsigned short*)(R2 + 4096);
    unsigned short* nd2 = (unsigned short*)(R2 + 6144);
    if (tid == 0)      { cn[0] = 0; cd[0] = 0; }
    else if (tid < NR) { cn[tid] = (unsigned short)myNr; cd[tid] = (unsigned short)myLen; }
    else               { cn[tid] = (unsigned short)tid; cd[tid] = 0; }
    __syncthreads();
    for (int r = 0; r < 10; r++) {
        int c = cn[tid];
        int dv = cd[tid] + cd[c];
        int n2 = cn[c];
        nn2[tid] = (unsigned short)n2; nd2[tid] = (unsigned short)dv;
        __syncthreads();
        unsigned short* t;
        t = cn; cn = nn2; nn2 = t;
        t = cd; cd = nd2; nd2 = t;
    }
    unsigned short* rb = nn2;
    rb[tid] = (tid == 0) ? 0 : (unsigned short)(TL - cd[tid]);
    __syncthreads();

    // ---- P4: per-element rank0 -> global ----
    for (int e = tid; e < TL; e += 1024) {
        unsigned int pk = elemSegG[e];
        rank0G[e] = (unsigned short)(rb[pk >> 11] + (pk & 2047));
    }
    __syncthreads();

    // ---- rounds: root 0 -> u -> v -> center ----
    int curRoot = 0, diam = 0, rootC = 0;
    for (int ph = 0; ph < 4; ph++) {
        if (tid == 0) {
            sInt = rank0G[degOff[curRoot]];
            sPack = 0; sCenter = 0; sMax = 0;
        }
        __syncthreads();
        const int R0r = sInt;
        const bool writeP = (ph == 3);
        // sign pass (+ parent info in final round)
        for (int j = tid; j < TL; j += 1024) {
            int r0 = rank0G[j];
            int ro = rank0G[oppG[j]];
            int rr = r0 - R0r;  if (rr < 0)  rr += TL;
            int rro = ro - R0r; if (rro < 0) rro += TL;
            bool desc = rr < rro;
            sgnG[rr] = desc ? 1 : -1;
            if (writeP && desc) {
                int own = ownG[j]; int u = own >> 2, d = own & 3;
                int v = u + dir_delta(d);
                pinfoG[v] = ((unsigned)(d ^ 1) << 15) | (unsigned)rr;
            }
        }
        __syncthreads();
        // +-1 inclusive scan over rotated tour -> scanS[rank] = depth(head)
        short* scanS = (short*)R0;
        {
            int base = tid * 18;
            int n = TL - base; if (n > 18) n = 18; if (n < 0) n = 0;
            int s = 0;
            for (int k = 0; k < n; k++) { s += sgnG[base + k]; scanS[base + k] = (short)s; }
            int incl = scan1024_incl(s, tid, (int*)R2, (int*)(R2 + 4096));
            int eb = incl - s;
            for (int k = 0; k < n; k++) scanS[base + k] = (short)(scanS[base + k] + eb);
        }
        __syncthreads();
        // gather depth per node via in-arc
        for (int x = tid; x < Nn; x += 1024) {
            int inj = oppG[degOff[x]];
            int rr = rank0G[inj] - R0r; if (rr < 0) rr += TL;
            int dep = (x == curRoot) ? 0 : scanS[rr];
            if (ph <= 1) atomicMax(&sPack, (dep << 14) | x);
            if (ph == 1) pinfoG[x] = (unsigned)dep;           // depth_u scratch
            if (ph == 2) {
                int du = (int)pinfoG[x];
                if (du + dep == diam && du == (diam >> 1)) atomicExch(&sCenter, x);
            }
            if (ph == 3) {
                ((unsigned short*)R1)[x] = (unsigned short)dep;  // own slot only
                atomicMax(&sMax, dep);
            }
        }
        __syncthreads();
        if (ph == 0)      curRoot = sPack & 16383;
        else if (ph == 1) { diam = sPack >> 14; curRoot = sPack & 16383; }
        else if (ph == 2) { curRoot = sCenter; rootC = curRoot; }
        __syncthreads();   // everyone read results before next-phase reset
    }
    const int D = sMax + 1;
    unsigned short* depthS = (unsigned short*)R1;   // overlays degOff (dead)

    // ---- counting sort by depth (center root) ----
    int* hist = (int*)R2;                            // int[2048]
    for (int k = tid; k < 2048; k += 1024) hist[k] = 0;
    __syncthreads();
    for (int v = tid; v < Nn; v += 1024) atomicAdd(&hist[depthS[v]], 1);
    __syncthreads();
    int* levOff = (int*)(R0 + 8192);                 // int[2048]
    {
        int h0 = hist[2 * tid], h1 = hist[2 * tid + 1];
        int partial = h0 + h1;
        int incl = scan1024_incl(partial, tid, (int*)R0, (int*)(R0 + 4096));
        int eb = incl - partial;
        levOff[2 * tid] = eb;
        levOff[2 * tid + 1] = eb + h0;
    }
    __syncthreads();
    for (int d = tid; d <= D && d < 2048; d += 1024) levG[d] = levOff[d];
    for (int k = tid; k < 2048; k += 1024) hist[k] = 0;
    __syncthreads();
    unsigned short* posOfS = (unsigned short*)(R0 + 16384);
    for (int v = tid; v < Nn; v += 1024) {
        int dep = depthS[v];
        int pos = levOff[dep] + atomicAdd(&hist[dep], 1);
        posOfS[v] = (unsigned short)pos;
        ordG[pos] = v;
    }
    __syncthreads();

    // ---- ppos + filter weights ----
    for (int v = tid; v < Nn; v += 1024) {
        int pos = posOfS[v];
        if (v == rootC) { pposG[pos] = 0; wgtG[pos] = 0.0f; }
        else {
            unsigned int pi = pinfoG[v];
            int rd = (int)(pi >> 15);
            int p = v + dir_delta(rd);
            pposG[pos] = posOfS[p];
            wgtG[pos] = expf(-(float)ew[edge_of(v, rd)] * inv_sigma);
        }
    }
    if (tid == 0) dG[tb] = D;
}

// Single-wave two-pass tree DP for one (batch, channel); wgt prefetched.
__global__ void __launch_bounds__(64)
k_dp(char* __restrict__ ws, int tree, int inMode) {
    const int bc = blockIdx.x;
    const int b = bc / NCh, c = bc % NCh;
    const int tb = tree * Bn + b;
    const int lane = threadIdx.x;
    const int*            ordG  = (const int*)(ws + OFF_ORD)  + (size_t)tb * Nn;
    const unsigned short* pposG = (const unsigned short*)(ws + OFF_PPOS) + (size_t)tb * Nn;
    const float*          wgtG  = (const float*)(ws + OFF_WGT) + (size_t)tb * Nn;
    const int*            levG  = (const int*)(ws + OFF_LEV)  + (size_t)tb * MAXD;
    const int D = ((const int*)(ws + OFF_D))[tb];
    const float* src = (inMode == 0)
        ? (const float*)(ws + OFF_PROB) + ((size_t)b * Cc + c) * Nn
        : (const float*)(ws + OFF_S1)   + ((size_t)b * NCh + c) * Nn;
    float* dst = (float*)(ws + (tree ? OFF_S2 : OFF_S1)) + ((size_t)b * NCh + c) * Nn;

    __shared__ alignas(16) float Al[Nn];
    __shared__ alignas(16) unsigned short pposS[Nn];
    __shared__ unsigned short levS[MAXD];

    {
        const uint4* pg4 = (const uint4*)pposG;
        uint4* ps4 = (uint4*)pposS;
        for (int k = lane; k < Nn / 8; k += 64) ps4[k] = pg4[k];
    }
    for (int d = lane; d <= D; d += 64) levS[d] = (unsigned short)levG[d];
    if (c == Cc) { for (int i = lane; i < Nn; i += 64) Al[i] = 1.0f; }
    else         { for (int i = lane; i < Nn; i += 64) Al[i] = src[ordG[i]]; }
    __syncthreads();

    // up: children before parents (ds_add_f32, no return)
    {
        int d = D - 1;
        int s0 = levS[d], s1 = levS[d + 1];
        float wq = (s0 + lane < s1) ? wgtG[s0 + lane] : 0.0f;
        for (; d >= 1; d--) {
            s0 = levS[d]; s1 = levS[d + 1];
            float wq_next = 0.0f;
            if (d > 1) {
                int p0 = levS[d - 1];
                if (p0 + lane < s0) wq_next = wgtG[p0 + lane];
            }
            int i = s0 + lane;
            if (i < s1) atomicAdd(&Al[pposS[i]], wq * Al[i]);
            for (i = s0 + lane + 64; i < s1; i += 64)
                atomicAdd(&Al[pposS[i]], wgtG[i] * Al[i]);
            __syncthreads();
            wq = wq_next;
        }
    }
    // down: parents before children
    if (D > 1) {
        int s0 = levS[1], s1 = levS[2 <= D ? 2 : 1];
        float wq = (s0 + lane < s1) ? wgtG[s0 + lane] : 0.0f;
        for (int d = 1; d < D; d++) {
            s0 = levS[d]; s1 = levS[d + 1];
            float wq_next = 0.0f;
            if (d + 1 < D) {
                int n0 = levS[d + 1], n1 = levS[d + 2];
                if (n0 + lane < n1) wq_next = wgtG[n0 + lane];
            }
            int i = s0 + lane;
            if (i < s1) { float w = wq, a = Al[i]; Al[i] = a + w * (Al[pposS[i]] - w * a); }
            for (i = s0 + lane + 64; i < s1; i += 64) {
                float w = wgtG[i], a = Al[i];
                Al[i] = a + w * (Al[pposS[i]] - w * a);
            }
            __syncthreads();
            wq = wq_next;
        }
    }
    for (int i = lane; i < Nn; i += 64) dst[ordG[i]] = Al[i];
}

// normalize S1 channels by norm channel
__global__ void k_norm(char* __restrict__ ws) {
    int idx = blockIdx.x * 256 + threadIdx.x;
    if (idx >= Bn * Cc * Nn) return;
    int b = idx / (Cc * Nn), rem = idx - b * (Cc * Nn);
    int c = rem / Nn, n = rem - c * Nn;
    float* S1 = (float*)(ws + OFF_S1);
    S1[((size_t)b * NCh + c) * Nn + n] /= S1[((size_t)b * NCh + Cc) * Nn + n];
}

__global__ void k_loss(char* __restrict__ ws, const float* __restrict__ roi) {
    const int tid = threadIdx.x;
    int idx = blockIdx.x * 256 + tid;
    const float* prob = (const float*)(ws + OFF_PROB);
    const float* S2   = (const float*)(ws + OFF_S2);
    double* acc = (double*)(ws + OFF_ACC);
    double ls = 0.0, cnt = 0.0;
    if (idx < Bn * Cc * Nn) {
        int b = idx / (Cc * Nn);
        int rem = idx - b * (Cc * Nn);
        int c = rem / Nn, n = rem - c * Nn;
        int h = n / Ww, w2 = n - h * Ww;
        float r = roi[(size_t)b * (2 * Hh) * (2 * Ww) + (size_t)(2 * h) * (2 * Ww) + 2 * w2];
        float as = S2[((size_t)b * NCh + c) * Nn + n] / S2[((size_t)b * NCh + Cc) * Nn + n];
        float pp = prob[((size_t)b * Cc + c) * Nn + n];
        ls = (double)(r * fabsf(pp - as));
        if (c == 0) cnt = (double)r;
    }
    __shared__ double sl[256], sc2[256];
    sl[tid] = ls; sc2[tid] = cnt;
    __syncthreads();
    for (int s = 128; s > 0; s >>= 1) {
        if (tid < s) { sl[tid] += sl[tid + s]; sc2[tid] += sc2[tid + s]; }
        __syncthreads();
    }
    if (tid == 0) { atomicAdd(acc, sl[0]); atomicAdd(acc + 1, sc2[0]); }
}

__global__ void k_final(const double* __restrict__ acc, float* __restrict__ out) {
    if (blockIdx.x == 0 && threadIdx.x == 0)
        out[0] = (acc[1] > 0.0) ? (float)(acc[0] / acc[1]) : 0.0f;
}

extern "C" void kernel_launch(void* const* d_in, const int* in_sizes, int n_in,
                              void* d_out, int out_size, void* d_ws, size_t ws_size,
                              hipStream_t stream) {
    const float* preds = (const float*)d_in[0];
    const float* lowf  = (const float*)d_in[1];
    const float* highf = (const float*)d_in[2];
    const float* roi   = (const float*)d_in[3];
    char* ws = (char*)d_ws;
    float* out = (float*)d_out;
    double* ewl = (double*)(ws + OFF_EW);
    double* ewh = (double*)(ws + OFF_EW) + (size_t)Bn * Ne;

    k_init<<<(Bn * Cc * Nn + 255) / 256, 256, 0, stream>>>(
        preds, (float*)(ws + OFF_PROB), (double*)(ws + OFF_ACC));
    k_edgew<<<(Bn * Ne + 255) / 256, 256, 0, stream>>>(lowf, Clow, ewl);
    k_edgew<<<(Bn * Ne + 255) / 256, 256, 0, stream>>>(highf, Chigh, ewh);
    k_mst<<<8, 1024, 0, stream>>>(ws);
    k_topo<<<8, 1024, 0, stream>>>(ws);
    k_dp<<<Bn * NCh, 64, 0, stream>>>(ws, 0, 0);
    k_norm<<<(Bn * Cc * Nn + 255) / 256, 256, 0, stream>>>(ws);
    k_dp<<<Bn * NCh, 64, 0, stream>>>(ws, 1, 1);
    k_loss<<<(Bn * Cc * Nn + 255) / 256, 256, 0, stream>>>(ws, roi);
    k_final<<<1, 64, 0, stream>>>((const double*)(ws + OFF_ACC), out);
}

// Round 8
// 1020.951 us; speedup vs baseline: 1.5874x; 1.1449x over previous
//
#include <hip/hip_runtime.h>
#include <math.h>
#include <stdint.h>
#include <stddef.h>

// TreeEnergyLoss on gfx950 — R8: LDS-resident Boruvka via 64-bit order keys
// + compact component slots (kills k_mst's 17.8MB of global cb traffic).
//
//  * Order key = (uint49)(w * 2^46) << 15 | edge_id. Monotone in w (w < 8),
//    1.4e-14 absolute resolution; sub-resolution ties break by edge index =
//    reference's stable-sort tie-break. One LDS atomicMin replaces the
//    two-pass global (weight, index) scheme.
//  * Components relabeled to compact slots [0,nComp) each round (prefix scan)
//    -> cbK ull[4608] fits LDS; select/jump/relabel run over nComp slots.
//  * k_topo (Euler-tour + center rooting) and k_dp (single-wave) unchanged.

namespace {
constexpr int Bn  = 4, Cc = 21, Hh = 96, Ww = 96;
constexpr int Nn  = Hh * Ww;              // 9216
constexpr int EhE = Hh * (Ww - 1);        // 9120
constexpr int Ne  = EhE + (Hh - 1) * Ww;  // 18240
constexpr int Clow = 3, Chigh = 512;
constexpr int NCh = Cc + 1;               // 22
constexpr int MAXD = 2048;
constexpr int TL  = 2 * (Nn - 1);         // 18430 arcs
constexpr int ESL = 18432;
constexpr int SEG = 19;                   // ruler stride (odd)
constexpr int NR  = (TL + SEG - 1) / SEG; // 970 rulers
constexpr int MAXC = 4608;                // max comps after round 1

// workspace layout (bytes) — 16B-aligned
constexpr size_t OFF_ACC  = 0;                                        // 2 doubles
constexpr size_t OFF_PROB = 256;                                      // float[B][21][Nn]
constexpr size_t OFF_S1   = OFF_PROB + (size_t)Bn * Cc * Nn * 4;      // float[B][22][Nn]
constexpr size_t OFF_S2   = OFF_S1   + (size_t)Bn * NCh * Nn * 4;     // float[B][22][Nn]
constexpr size_t OFF_EW   = OFF_S2   + (size_t)Bn * NCh * Nn * 4;     // double[8][Ne]
constexpr size_t OFF_ORD  = OFF_EW   + (size_t)8 * Ne * 8;            // int[8][Nn]
constexpr size_t OFF_PPOS = OFF_ORD  + (size_t)8 * Nn * 4;            // ushort[8][Nn]
constexpr size_t OFF_WGT  = OFF_PPOS + (size_t)8 * Nn * 2;            // float[8][Nn]
constexpr size_t OFF_LEV  = OFF_WGT  + (size_t)8 * Nn * 4;            // int[8][MAXD]
constexpr size_t OFF_D    = OFF_LEV  + (size_t)8 * MAXD * 4;          // int[8]
constexpr size_t OFF_DIR  = OFF_D    + 256;                           // int[8][Nn]
constexpr size_t OFF_CBW  = OFF_DIR  + (size_t)8 * Nn * 4;            // uint[8][ESL] (k_topo)
constexpr size_t OFF_CBE  = OFF_CBW  + (size_t)8 * Nn * 8;            // ushort[8][ESL] (k_topo)
constexpr size_t OFF_OPP  = OFF_CBE  + (size_t)8 * Nn * 4;            // ushort[8][ESL]
constexpr size_t OFF_SGN  = OFF_OPP  + (size_t)8 * ESL * 2;           // int8[8][ESL]
constexpr size_t OFF_PNF  = OFF_SGN  + (size_t)8 * ESL;               // uint[8][Nn]
constexpr size_t OFF_RNK  = OFF_PNF  + (size_t)8 * Nn * 4;            // ushort[8][ESL]
// k_mst edge-list ping/pong overlaid on regions dead until k_topo:
constexpr size_t OFF_EL1  = OFF_ORD;                                  // ushort[8][Ne]
constexpr size_t OFF_EL2  = OFF_WGT;                                  // ushort[8][Ne]
} // namespace

__device__ __forceinline__ void edge_nodes(int e, int& a, int& b) {
    if (e < EhE) { int h = e / (Ww - 1), w = e - h * (Ww - 1); a = h * Ww + w; b = a + 1; }
    else { int e2 = e - EhE; int h = e2 / Ww, w = e2 - h * Ww; a = h * Ww + w; b = a + Ww; }
}
// dirs: 0=E(+1) 1=W(-1) 2=S(+96) 3=N(-96); rev(d)=d^1
__device__ __forceinline__ int dir_delta(int d) {
    return (d == 0) ? 1 : (d == 1) ? -1 : (d == 2) ? Ww : -Ww;
}
__device__ __forceinline__ int edge_of(int u, int d) {
    int h = u / Ww, w = u - h * Ww;
    if (d == 0) return h * (Ww - 1) + w;
    if (d == 1) return h * (Ww - 1) + w - 1;
    if (d == 2) return EhE + u;
    return EhE + u - Ww;
}

// 64-bit total-order key: (fixed-point weight, edge index)
__device__ __forceinline__ unsigned long long mkkey(double w, int e) {
    unsigned long long q = (unsigned long long)(w * 70368744177664.0);  // 2^46
    if (q >= (1ull << 49)) q = (1ull << 49) - 1;
    return (q << 15) | (unsigned)e;
}

// wave-aggregated compaction push (1 LDS atomic per wave instead of 64)
__device__ __forceinline__ void compact_push(bool keep, int val, int* cnt,
                                             unsigned short* out, int lane) {
    unsigned long long m = __ballot(keep ? 1 : 0);
    if (m == 0ull) return;
    int leader = __ffsll((unsigned long long)m) - 1;
    int base = 0;
    if (lane == leader) base = atomicAdd(cnt, __popcll(m));
    base = __shfl(base, leader, 64);
    if (keep) {
        unsigned long long lower = m & ((1ull << lane) - 1ull);
        out[base + __popcll(lower)] = (unsigned short)val;
    }
}

// inclusive block scan of 1024 ints; b0/b1 are int[1024]
__device__ __forceinline__ int scan1024_incl(int val, int tid, int* b0, int* b1) {
    b0[tid] = val;
    __syncthreads();
    int* s = b0; int* d = b1;
    for (int off = 1; off < 1024; off <<= 1) {
        int x = s[tid];
        if (tid >= off) x += s[tid - off];
        d[tid] = x;
        __syncthreads();
        int* t = s; s = d; d = t;
    }
    return s[tid];
}

__global__ void k_init(const float* __restrict__ preds, float* __restrict__ prob,
                       double* __restrict__ acc) {
    int idx = blockIdx.x * blockDim.x + threadIdx.x;
    if (idx == 0) { acc[0] = 0.0; acc[1] = 0.0; }
    if (idx >= Bn * Cc * Nn) return;
    prob[idx] = 1.0f / (1.0f + expf(-preds[idx]));
}

// exact float64 edge weights: sequential channel sum matches numpy axis-0 reduce
__global__ void k_edgew(const float* __restrict__ feat, int C, double* __restrict__ ew) {
    int idx = blockIdx.x * blockDim.x + threadIdx.x;
    if (idx >= Bn * Ne) return;
    int b = idx / Ne, e = idx - b * Ne;
    int a, c2; edge_nodes(e, a, c2);
    const float* f = feat + (size_t)b * C * Nn;
    double s = 0.0;
    for (int c = 0; c < C; c++) {
        double d = (double)f[(size_t)c * Nn + a] - (double)f[(size_t)c * Nn + c2];
        s += d * d;
    }
    ew[idx] = s;
}

// Boruvka MST, LDS-resident. One block per (tree,batch) tb.
__global__ void __launch_bounds__(1024)
k_mst(char* __restrict__ ws) {
    const int tb = blockIdx.x, tid = threadIdx.x;
    const int lane = tid & 63;
    const double* ew = (const double*)(ws + OFF_EW) + (size_t)tb * Ne;
    int* dirG = (int*)(ws + OFF_DIR) + (size_t)tb * Nn;
    unsigned short* elA = (unsigned short*)(ws + OFF_EL1) + (size_t)tb * Ne;
    unsigned short* elB = (unsigned short*)(ws + OFF_EL2) + (size_t)tb * Ne;

    __shared__ unsigned short comp[Nn];            // 18432 B
    __shared__ unsigned long long cbK[MAXC];       // 36864 B (overlaid below)
    __shared__ int scanBuf[2048];                  // 8192 B
    __shared__ int chgArr[48];
    __shared__ int sLen, sNC;

    // overlays of the cbK region (used when cbK itself is dead):
    unsigned short* nxtN     = (unsigned short*)cbK;          // [Nn] round 1
    unsigned short* newSlotN = (unsigned short*)cbK + Nn;     // [Nn] round 1
    unsigned short* nxt      = (unsigned short*)cbK;          // [MAXC] rounds>=2
    unsigned short* newSlot  = (unsigned short*)cbK + MAXC;   // [MAXC] rounds>=2

    for (int i = tid; i < Nn; i += 1024) dirG[i] = 0;
    if (tid < 48) chgArr[tid] = 0;
    __syncthreads();

    // ---------- round 1: each node picks min incident edge (by key) ----------
    for (int i = tid; i < Nn; i += 1024) {
        int h = i / Ww, w = i - h * Ww;
        unsigned long long bk = ~0ull;
        if (w < Ww - 1) { int e = h * (Ww - 1) + w;     unsigned long long k = mkkey(ew[e], e); if (k < bk) bk = k; }
        if (w > 0)      { int e = h * (Ww - 1) + w - 1; unsigned long long k = mkkey(ew[e], e); if (k < bk) bk = k; }
        if (h < Hh - 1) { int e = EhE + i;              unsigned long long k = mkkey(ew[e], e); if (k < bk) bk = k; }
        if (h > 0)      { int e = EhE + i - Ww;         unsigned long long k = mkkey(ew[e], e); if (k < bk) bk = k; }
        int e = (int)(bk & 0x7FFF);
        int a, c; edge_nodes(e, a, c);
        nxtN[i] = (unsigned short)((a == i) ? c : a);
        int da = (c == a + 1) ? 0 : 2;
        atomicOr(&dirG[a], 1 << da);
        atomicOr(&dirG[c], 1 << (da ^ 1));
    }
    __syncthreads();
    for (int i = tid; i < Nn; i += 1024) {             // break 2-cycles
        int o = nxtN[i];
        if (o != i && nxtN[o] == i && i < o) nxtN[i] = (unsigned short)i;
    }
    __syncthreads();
    {   // pointer doubling over nodes
        int it = 0;
        while (it < 40) {
            bool any = false;
            for (int r = tid; r < Nn; r += 1024) {
                int nr = nxtN[r], nnr = nxtN[nr];
                if (nr != nnr) { nxtN[r] = (unsigned short)nnr; any = true; }
            }
            if (any) chgArr[it] = 1;
            __syncthreads();
            if (!chgArr[it]) break;
            it++;
        }
    }
    {   // relabel roots -> compact slots; comp[i] = slot of node i's root
        int base = tid * 9, cnt = 0, loc[9];
        #pragma unroll
        for (int k = 0; k < 9; k++) {
            int i = base + k;
            loc[k] = cnt;
            if (nxtN[i] == i) cnt++;
        }
        int incl = scan1024_incl(cnt, tid, scanBuf, scanBuf + 1024);
        int eb = incl - cnt;
        #pragma unroll
        for (int k = 0; k < 9; k++) {
            int i = base + k;
            if (nxtN[i] == i) newSlotN[i] = (unsigned short)(eb + loc[k]);
        }
        if (tid == 1023) sNC = incl;
    }
    __syncthreads();
    for (int i = tid; i < Nn; i += 1024) comp[i] = newSlotN[nxtN[i]];
    __syncthreads();
    int nComp = sNC;

    // ---------- rounds >= 2: compact slots + LDS key atomics ----------
    unsigned short* src = elA;
    unsigned short* dst = elB;
    int srcLen = -1;
    for (int round = 2; round < 22 && nComp > 1; round++) {
        if (tid == 0) sLen = 0;
        if (tid < 48) chgArr[tid] = 0;
        __syncthreads();
        // compact surviving inter-comp edges; init cbK for live slots
        if (srcLen < 0) {
            for (int e = tid; e < Ne; e += 1024) {
                int a, c; edge_nodes(e, a, c);
                compact_push(comp[a] != comp[c], e, &sLen, dst, lane);
            }
        } else {
            for (int k = tid; k < srcLen; k += 1024) {
                int e = src[k];
                int a, c; edge_nodes(e, a, c);
                compact_push(comp[a] != comp[c], e, &sLen, dst, lane);
            }
        }
        for (int s = tid; s < nComp; s += 1024) cbK[s] = ~0ull;
        __syncthreads();
        int len = sLen;
        if (len == 0) break;
        // single edge pass: atomicMin of 64-bit key per endpoint slot
        for (int k = tid; k < len; k += 1024) {
            int e = dst[k];
            int a, c; edge_nodes(e, a, c);
            unsigned long long key = mkkey(ew[e], e);
            atomicMin(&cbK[comp[a]], key);
            atomicMin(&cbK[comp[c]], key);
        }
        __syncthreads();
        // select: read own keys first (cbK region gets overlaid by nxt)
        unsigned long long kr[5];
        int nOwn = 0;
        for (int s = tid; s < nComp; s += 1024) kr[nOwn++] = cbK[s];
        __syncthreads();
        {
            int o = 0;
            for (int s = tid; s < nComp; s += 1024, o++) {
                unsigned long long key = kr[o];
                if (key != ~0ull) {
                    int e = (int)(key & 0x7FFF);
                    int a, c; edge_nodes(e, a, c);
                    int sa = comp[a], sc = comp[c];
                    nxt[s] = (unsigned short)((sa == s) ? sc : sa);
                    int da = (c == a + 1) ? 0 : 2;
                    atomicOr(&dirG[a], 1 << da);
                    atomicOr(&dirG[c], 1 << (da ^ 1));
                } else nxt[s] = (unsigned short)s;
            }
        }
        __syncthreads();
        for (int s = tid; s < nComp; s += 1024) {      // break 2-cycles
            int o = nxt[s];
            if (o != s && nxt[o] == s && s < o) nxt[s] = (unsigned short)s;
        }
        __syncthreads();
        {   // pointer doubling over slots
            int it = 0;
            while (it < 40) {
                bool any = false;
                for (int s = tid; s < nComp; s += 1024) {
                    int ns = nxt[s], nns = nxt[ns];
                    if (ns != nns) { nxt[s] = (unsigned short)nns; any = true; }
                }
                if (any) chgArr[it] = 1;
                __syncthreads();
                if (!chgArr[it]) break;
                it++;
            }
        }
        {   // relabel merged roots -> new compact slots
            int K = (nComp + 1023) >> 10;
            int base = tid * K, cnt = 0, loc[5];
            for (int k = 0; k < K; k++) {
                int s = base + k;
                loc[k] = cnt;
                if (s < nComp && nxt[s] == s) cnt++;
            }
            int incl = scan1024_incl(cnt, tid, scanBuf, scanBuf + 1024);
            int eb = incl - cnt;
            for (int k = 0; k < K; k++) {
                int s = base + k;
                if (s < nComp && nxt[s] == s) newSlot[s] = (unsigned short)(eb + loc[k]);
            }
            if (tid == 1023) sNC = incl;
        }
        __syncthreads();
        for (int i = tid; i < Nn; i += 1024) comp[i] = newSlot[nxt[comp[i]]];
        __syncthreads();
        nComp = sNC;
        unsigned short* t = src; src = dst; dst = t;
        srcLen = len;
    }
}

// Euler-tour topology with CENTER rooting. Ranks once; 4 rotation-scan rounds.
__global__ void __launch_bounds__(1024)
k_topo(char* __restrict__ ws) {
    const int tb = blockIdx.x, tid = threadIdx.x;
    const int tree = tb >> 2;
    const double* ew  = (const double*)(ws + OFF_EW) + (size_t)tb * Ne;
    const int*  dirG  = (const int*)(ws + OFF_DIR) + (size_t)tb * Nn;
    unsigned int*   elemSegG = (unsigned int*)(ws + OFF_CBW) + (size_t)tb * ESL;
    unsigned short* ownG     = (unsigned short*)(ws + OFF_CBE) + (size_t)tb * ESL;
    unsigned short* oppG     = (unsigned short*)(ws + OFF_OPP) + (size_t)tb * ESL;
    signed char*    sgnG     = (signed char*)(ws + OFF_SGN) + (size_t)tb * ESL;
    unsigned int*   pinfoG   = (unsigned int*)(ws + OFF_PNF) + (size_t)tb * Nn;
    unsigned short* rank0G   = (unsigned short*)(ws + OFF_RNK) + (size_t)tb * ESL;
    int*            ordG  = (int*)(ws + OFF_ORD)  + (size_t)tb * Nn;
    unsigned short* pposG = (unsigned short*)(ws + OFF_PPOS) + (size_t)tb * Nn;
    float*          wgtG  = (float*)(ws + OFF_WGT) + (size_t)tb * Nn;
    int*            levG  = (int*)(ws + OFF_LEV)  + (size_t)tb * MAXD;
    int*            dG    = (int*)(ws + OFF_D);
    const float inv_sigma = tree ? 1.0f : 50.0f;

    __shared__ char SB[64512];           // R0:36864 | R1:18432 | R2:9216
    char* R0 = SB;
    char* R1 = SB + 36864;
    char* R2 = SB + 55296;
    __shared__ int sPack, sCenter, sInt, sMax;

    // ---- P0: masks -> LDS; degree prefix sums ----
    unsigned short* degOff = (unsigned short*)R1;
    unsigned char*  nbS    = (unsigned char*)R2;
    for (int i = tid; i < Nn; i += 1024) nbS[i] = (unsigned char)dirG[i];
    __syncthreads();
    {
        int base9 = tid * 9;
        int loc[9]; int s = 0;
        #pragma unroll
        for (int k = 0; k < 9; k++) { loc[k] = s; s += __popc(nbS[base9 + k]); }
        int incl = scan1024_incl(s, tid, (int*)R0, (int*)(R0 + 4096));
        int eb = incl - s;
        #pragma unroll
        for (int k = 0; k < 9; k++) degOff[base9 + k] = (unsigned short)(eb + loc[k]);
    }
    __syncthreads();

    // ---- P1: Euler successor + owner + opposite ----
    unsigned short* nxtS = (unsigned short*)R0;
    for (int u = tid; u < Nn; u += 1024) {
        int m = nbS[u]; int base = degOff[u]; int k = 0;
        #pragma unroll
        for (int d = 0; d < 4; d++) {
            if (m & (1 << d)) {
                int v = u + dir_delta(d);
                int mv = nbS[v]; int rd = d ^ 1;
                int pv = __popc(mv & ((1 << rd) - 1));
                int dv = __popc(mv);
                int nx = pv + 1; if (nx == dv) nx = 0;
                int j = base + k;
                nxtS[j] = (unsigned short)(degOff[v] + nx);
                ownG[j] = (unsigned short)((u << 2) | d);
                oppG[j] = (unsigned short)(degOff[v] + pv);
                k++;
            }
        }
    }
    __syncthreads();

    // ---- P2: ruling-set walks ----
    int myNr = 0, myLen = 0;
    if (tid < NR) {
        int x = tid * SEG, off = 0;
        for (int g = 0; g < 4096; g++) {
            elemSegG[x] = ((unsigned)tid << 11) | (unsigned)off;
            int y = nxtS[x];
            if (y % SEG == 0) { myNr = y / SEG; myLen = off + 1; break; }
            x = y; off++;
        }
    }
    __syncthreads();

    // ---- P3: ruler pointer doubling (in R2; nbS dead) ----
    unsigned short* cn  = (unsigned short*)R2;
    unsigned short* cd  = (unsigned short*)(R2 + 2048);
    unsigned short* nn2 = (unsigned short*)(R2 + 4096);
    unsigned short* nd2 = (unsigned short*)(R2 + 6144);
    if (tid == 0)      { cn[0] = 0; cd[0] = 0; }
    else if (tid < NR) { cn[tid] = (unsigned short)myNr; cd[tid] = (unsigned short)myLen; }
    else               { cn[tid] = (unsigned short)tid; cd[tid] = 0; }
    __syncthreads();
    for (int r = 0; r < 10; r++) {
        int c = cn[tid];
        int dv = cd[tid] + cd[c];
        int n2 = cn[c];
        nn2[tid] = (unsigned short)n2; nd2[tid] = (unsigned short)dv;
        __syncthreads();
        unsigned short* t;
        t = cn; cn = nn2; nn2 = t;
        t = cd; cd = nd2; nd2 = t;
    }
    unsigned short* rb = nn2;
    rb[tid] = (tid == 0) ? 0 : (unsigned short)(TL - cd[tid]);
    __syncthreads();

    // ---- P4: per-element rank0 -> global ----
    for (int e = tid; e < TL; e += 1024) {
        unsigned int pk = elemSegG[e];
        rank0G[e] = (unsigned short)(rb[pk >> 11] + (pk & 2047));
    }
    __syncthreads();

    // ---- rounds: root 0 -> u -> v -> center ----
    int curRoot = 0, diam = 0, rootC = 0;
    for (int ph = 0; ph < 4; ph++) {
        if (tid == 0) {
            sInt = rank0G[degOff[curRoot]];
            sPack = 0; sCenter = 0; sMax = 0;
        }
        __syncthreads();
        const int R0r = sInt;
        const bool writeP = (ph == 3);
        for (int j = tid; j < TL; j += 1024) {
            int r0 = rank0G[j];
            int ro = rank0G[oppG[j]];
            int rr = r0 - R0r;  if (rr < 0)  rr += TL;
            int rro = ro - R0r; if (rro < 0) rro += TL;
            bool desc = rr < rro;
            sgnG[rr] = desc ? 1 : -1;
            if (writeP && desc) {
                int own = ownG[j]; int u = own >> 2, d = own & 3;
                int v = u + dir_delta(d);
                pinfoG[v] = ((unsigned)(d ^ 1) << 15) | (unsigned)rr;
            }
        }
        __syncthreads();
        short* scanS = (short*)R0;
        {
            int base = tid * 18;
            int n = TL - base; if (n > 18) n = 18; if (n < 0) n = 0;
            int s = 0;
            for (int k = 0; k < n; k++) { s += sgnG[base + k]; scanS[base + k] = (short)s; }
            int incl = scan1024_incl(s, tid, (int*)R2, (int*)(R2 + 4096));
            int eb = incl - s;
            for (int k = 0; k < n; k++) scanS[base + k] = (short)(scanS[base + k] + eb);
        }
        __syncthreads();
        for (int x = tid; x < Nn; x += 1024) {
            int inj = oppG[degOff[x]];
            int rr = rank0G[inj] - R0r; if (rr < 0) rr += TL;
            int dep = (x == curRoot) ? 0 : scanS[rr];
            if (ph <= 1) atomicMax(&sPack, (dep << 14) | x);
            if (ph == 1) pinfoG[x] = (unsigned)dep;
            if (ph == 2) {
                int du = (int)pinfoG[x];
                if (du + dep == diam && du == (diam >> 1)) atomicExch(&sCenter, x);
            }
            if (ph == 3) {
                ((unsigned short*)R1)[x] = (unsigned short)dep;
                atomicMax(&sMax, dep);
            }
        }
        __syncthreads();
        if (ph == 0)      curRoot = sPack & 16383;
        else if (ph == 1) { diam = sPack >> 14; curRoot = sPack & 16383; }
        else if (ph == 2) { curRoot = sCenter; rootC = curRoot; }
        __syncthreads();
    }
    const int D = sMax + 1;
    unsigned short* depthS = (unsigned short*)R1;

    // ---- counting sort by depth (center root) ----
    int* hist = (int*)R2;
    for (int k = tid; k < 2048; k += 1024) hist[k] = 0;
    __syncthreads();
    for (int v = tid; v < Nn; v += 1024) atomicAdd(&hist[depthS[v]], 1);
    __syncthreads();
    int* levOff = (int*)(R0 + 8192);
    {
        int h0 = hist[2 * tid], h1 = hist[2 * tid + 1];
        int partial = h0 + h1;
        int incl = scan1024_incl(partial, tid, (int*)R0, (int*)(R0 + 4096));
        int eb = incl - partial;
        levOff[2 * tid] = eb;
        levOff[2 * tid + 1] = eb + h0;
    }
    __syncthreads();
    for (int d = tid; d <= D && d < 2048; d += 1024) levG[d] = levOff[d];
    for (int k = tid; k < 2048; k += 1024) hist[k] = 0;
    __syncthreads();
    unsigned short* posOfS = (unsigned short*)(R0 + 16384);
    for (int v = tid; v < Nn; v += 1024) {
        int dep = depthS[v];
        int pos = levOff[dep] + atomicAdd(&hist[dep], 1);
        posOfS[v] = (unsigned short)pos;
        ordG[pos] = v;
    }
    __syncthreads();

    // ---- ppos + filter weights ----
    for (int v = tid; v < Nn; v += 1024) {
        int pos = posOfS[v];
        if (v == rootC) { pposG[pos] = 0; wgtG[pos] = 0.0f; }
        else {
            unsigned int pi = pinfoG[v];
            int rd = (int)(pi >> 15);
            int p = v + dir_delta(rd);
            pposG[pos] = posOfS[p];
            wgtG[pos] = expf(-(float)ew[edge_of(v, rd)] * inv_sigma);
        }
    }
    if (tid == 0) dG[tb] = D;
}

// Single-wave two-pass tree DP for one (batch, channel); wgt prefetched.
__global__ void __launch_bounds__(64)
k_dp(char* __restrict__ ws, int tree, int inMode) {
    const int bc = blockIdx.x;
    const int b = bc / NCh, c = bc % NCh;
    const int tb = tree * Bn + b;
    const int lane = threadIdx.x;
    const int*            ordG  = (const int*)(ws + OFF_ORD)  + (size_t)tb * Nn;
    const unsigned short* pposG = (const unsigned short*)(ws + OFF_PPOS) + (size_t)tb * Nn;
    const float*          wgtG  = (const float*)(ws + OFF_WGT) + (size_t)tb * Nn;
    const int*            levG  = (const int*)(ws + OFF_LEV)  + (size_t)tb * MAXD;
    const int D = ((const int*)(ws + OFF_D))[tb];
    const float* src = (inMode == 0)
        ? (const float*)(ws + OFF_PROB) + ((size_t)b * Cc + c) * Nn
        : (const float*)(ws + OFF_S1)   + ((size_t)b * NCh + c) * Nn;
    float* dst = (float*)(ws + (tree ? OFF_S2 : OFF_S1)) + ((size_t)b * NCh + c) * Nn;

    __shared__ alignas(16) float Al[Nn];
    __shared__ alignas(16) unsigned short pposS[Nn];
    __shared__ unsigned short levS[MAXD];

    {
        const uint4* pg4 = (const uint4*)pposG;
        uint4* ps4 = (uint4*)pposS;
        for (int k = lane; k < Nn / 8; k += 64) ps4[k] = pg4[k];
    }
    for (int d = lane; d <= D; d += 64) levS[d] = (unsigned short)levG[d];
    if (c == Cc) { for (int i = lane; i < Nn; i += 64) Al[i] = 1.0f; }
    else         { for (int i = lane; i < Nn; i += 64) Al[i] = src[ordG[i]]; }
    __syncthreads();

    // up: children before parents (ds_add_f32, no return)
    {
        int d = D - 1;
        int s0 = levS[d], s1 = levS[d + 1];
        float wq = (s0 + lane < s1) ? wgtG[s0 + lane] : 0.0f;
        for (; d >= 1; d--) {
            s0 = levS[d]; s1 = levS[d + 1];
            float wq_next = 0.0f;
            if (d > 1) {
                int p0 = levS[d - 1];
                if (p0 + lane < s0) wq_next = wgtG[p0 + lane];
            }
            int i = s0 + lane;
            if (i < s1) atomicAdd(&Al[pposS[i]], wq * Al[i]);
            for (i = s0 + lane + 64; i < s1; i += 64)
                atomicAdd(&Al[pposS[i]], wgtG[i] * Al[i]);
            __syncthreads();
            wq = wq_next;
        }
    }
    // down: parents before children
    if (D > 1) {
        int s0 = levS[1], s1 = levS[2 <= D ? 2 : 1];
        float wq = (s0 + lane < s1) ? wgtG[s0 + lane] : 0.0f;
        for (int d = 1; d < D; d++) {
            s0 = levS[d]; s1 = levS[d + 1];
            float wq_next = 0.0f;
            if (d + 1 < D) {
                int n0 = levS[d + 1], n1 = levS[d + 2];
                if (n0 + lane < n1) wq_next = wgtG[n0 + lane];
            }
            int i = s0 + lane;
            if (i < s1) { float w = wq, a = Al[i]; Al[i] = a + w * (Al[pposS[i]] - w * a); }
            for (i = s0 + lane + 64; i < s1; i += 64) {
                float w = wgtG[i], a = Al[i];
                Al[i] = a + w * (Al[pposS[i]] - w * a);
            }
            __syncthreads();
            wq = wq_next;
        }
    }
    for (int i = lane; i < Nn; i += 64) dst[ordG[i]] = Al[i];
}

// normalize S1 channels by norm channel
__global__ void k_norm(char* __restrict__ ws) {
    int idx = blockIdx.x * 256 + threadIdx.x;
    if (idx >= Bn * Cc * Nn) return;
    int b = idx / (Cc * Nn), rem = idx - b * (Cc * Nn);
    int c = rem / Nn, n = rem - c * Nn;
    float* S1 = (float*)(ws + OFF_S1);
    S1[((size_t)b * NCh + c) * Nn + n] /= S1[((size_t)b * NCh + Cc) * Nn + n];
}

__global__ void k_loss(char* __restrict__ ws, const float* __restrict__ roi) {
    const int tid = threadIdx.x;
    int idx = blockIdx.x * 256 + tid;
    const float* prob = (const float*)(ws + OFF_PROB);
    const float* S2   = (const float*)(ws + OFF_S2);
    double* acc = (double*)(ws + OFF_ACC);
    double ls = 0.0, cnt = 0.0;
    if (idx < Bn * Cc * Nn) {
        int b = idx / (Cc * Nn);
        int rem = idx - b * (Cc * Nn);
        int c = rem / Nn, n = rem - c * Nn;
        int h = n / Ww, w2 = n - h * Ww;
        float r = roi[(size_t)b * (2 * Hh) * (2 * Ww) + (size_t)(2 * h) * (2 * Ww) + 2 * w2];
        float as = S2[((size_t)b * NCh + c) * Nn + n] / S2[((size_t)b * NCh + Cc) * Nn + n];
        float pp = prob[((size_t)b * Cc + c) * Nn + n];
        ls = (double)(r * fabsf(pp - as));
        if (c == 0) cnt = (double)r;
    }
    __shared__ double sl[256], sc2[256];
    sl[tid] = ls; sc2[tid] = cnt;
    __syncthreads();
    for (int s = 128; s > 0; s >>= 1) {
        if (tid < s) { sl[tid] += sl[tid + s]; sc2[tid] += sc2[tid + s]; }
        __syncthreads();
    }
    if (tid == 0) { atomicAdd(acc, sl[0]); atomicAdd(acc + 1, sc2[0]); }
}

__global__ void k_final(const double* __restrict__ acc, float* __restrict__ out) {
    if (blockIdx.x == 0 && threadIdx.x == 0)
        out[0] = (acc[1] > 0.0) ? (float)(acc[0] / acc[1]) : 0.0f;
}

extern "C" void kernel_launch(void* const* d_in, const int* in_sizes, int n_in,
                              void* d_out, int out_size, void* d_ws, size_t ws_size,
                              hipStream_t stream) {
    const float* preds = (const float*)d_in[0];
    const float* lowf  = (const float*)d_in[1];
    const float* highf = (const float*)d_in[2];
    const float* roi   = (const float*)d_in[3];
    char* ws = (char*)d_ws;
    float* out = (float*)d_out;
    double* ewl = (double*)(ws + OFF_EW);
    double* ewh = (double*)(ws + OFF_EW) + (size_t)Bn * Ne;

    k_init<<<(Bn * Cc * Nn + 255) / 256, 256, 0, stream>>>(
        preds, (float*)(ws + OFF_PROB), (double*)(ws + OFF_ACC));
    k_edgew<<<(Bn * Ne + 255) / 256, 256, 0, stream>>>(lowf, Clow, ewl);
    k_edgew<<<(Bn * Ne + 255) / 256, 256, 0, stream>>>(highf, Chigh, ewh);
    k_mst<<<8, 1024, 0, stream>>>(ws);
    k_topo<<<8, 1024, 0, stream>>>(ws);
    k_dp<<<Bn * NCh, 64, 0, stream>>>(ws, 0, 0);
    k_norm<<<(Bn * Cc * Nn + 255) / 256, 256, 0, stream>>>(ws);
    k_dp<<<Bn * NCh, 64, 0, stream>>>(ws, 1, 1);
    k_loss<<<(Bn * Cc * Nn + 255) / 256, 256, 0, stream>>>(ws, roi);
    k_final<<<1, 64, 0, stream>>>((const double*)(ws + OFF_ACC), out);
}

// Round 9
// 993.815 us; speedup vs baseline: 1.6307x; 1.0273x over previous
//
#include <hip/hip_runtime.h>
#include <math.h>
#include <stdint.h>
#include <stddef.h>

// TreeEnergyLoss on gfx950 — R9: k_topo rounds restructured.
//
//  * Rank-space reindex (ORG/OWNR by rank, IRG per node) -> each root round is
//    ONE fused sign+scan pass (coalesced global reads, shfl block scan, LDS
//    scanS) + one gather pass. No sgn scatter/rescan, no dependent gathers.
//  * 3 rounds, not 4: center found by a parent-walk from v (LDS, ~diam/2 hops)
//    instead of a third BFS round.
//  * Per-wave shfl max-reduce before sPack atomics (was 9216 serialized).
//  * k_norm folded into k_dp's gather. k_mst/k_dp core unchanged from R8.

namespace {
constexpr int Bn  = 4, Cc = 21, Hh = 96, Ww = 96;
constexpr int Nn  = Hh * Ww;              // 9216
constexpr int EhE = Hh * (Ww - 1);        // 9120
constexpr int Ne  = EhE + (Hh - 1) * Ww;  // 18240
constexpr int Clow = 3, Chigh = 512;
constexpr int NCh = Cc + 1;               // 22
constexpr int MAXD = 2048;
constexpr int TL  = 2 * (Nn - 1);         // 18430 arcs
constexpr int ESL = 18432;
constexpr int SEG = 19;                   // ruler stride (odd)
constexpr int NR  = (TL + SEG - 1) / SEG; // 970 rulers
constexpr int MAXC = 4608;

// workspace layout (bytes) — 16B-aligned
constexpr size_t OFF_ACC  = 0;                                        // 2 doubles
constexpr size_t OFF_PROB = 256;                                      // float[B][21][Nn]
constexpr size_t OFF_S1   = OFF_PROB + (size_t)Bn * Cc * Nn * 4;      // float[B][22][Nn]
constexpr size_t OFF_S2   = OFF_S1   + (size_t)Bn * NCh * Nn * 4;     // float[B][22][Nn]
constexpr size_t OFF_EW   = OFF_S2   + (size_t)Bn * NCh * Nn * 4;     // double[8][Ne]
constexpr size_t OFF_ORD  = OFF_EW   + (size_t)8 * Ne * 8;            // int[8][Nn]
constexpr size_t OFF_PPOS = OFF_ORD  + (size_t)8 * Nn * 4;            // ushort[8][Nn]
constexpr size_t OFF_WGT  = OFF_PPOS + (size_t)8 * Nn * 2;            // float[8][Nn]
constexpr size_t OFF_LEV  = OFF_WGT  + (size_t)8 * Nn * 4;            // int[8][MAXD]
constexpr size_t OFF_D    = OFF_LEV  + (size_t)8 * MAXD * 4;          // int[8]
constexpr size_t OFF_DIR  = OFF_D    + 256;                           // int[8][Nn]
constexpr size_t OFF_CBW  = OFF_DIR  + (size_t)8 * Nn * 4;            // 73728 B/tb: elemSeg | ORG+OWNR
constexpr size_t OFF_CBE  = OFF_CBW  + (size_t)8 * Nn * 8;            // ushort[8][ESL] ownG
constexpr size_t OFF_OPP  = OFF_CBE  + (size_t)8 * Nn * 4;            // ushort[8][ESL] oppG
constexpr size_t OFF_SGN  = OFF_OPP  + (size_t)8 * ESL * 2;           // 18432 B/tb: IRG ushort[Nn]
constexpr size_t OFF_PNF  = OFF_SGN  + (size_t)8 * ESL;               // uint[8][Nn] (unused)
constexpr size_t OFF_RNK  = OFF_PNF  + (size_t)8 * Nn * 4;            // ushort[8][ESL] rank0
// k_mst edge-list ping/pong overlaid on regions dead until k_topo:
constexpr size_t OFF_EL1  = OFF_ORD;                                  // ushort[8][Ne]
constexpr size_t OFF_EL2  = OFF_WGT;                                  // ushort[8][Ne]
} // namespace

__device__ __forceinline__ void edge_nodes(int e, int& a, int& b) {
    if (e < EhE) { int h = e / (Ww - 1), w = e - h * (Ww - 1); a = h * Ww + w; b = a + 1; }
    else { int e2 = e - EhE; int h = e2 / Ww, w = e2 - h * Ww; a = h * Ww + w; b = a + Ww; }
}
// dirs: 0=E(+1) 1=W(-1) 2=S(+96) 3=N(-96); rev(d)=d^1
__device__ __forceinline__ int dir_delta(int d) {
    return (d == 0) ? 1 : (d == 1) ? -1 : (d == 2) ? Ww : -Ww;
}
__device__ __forceinline__ int edge_of(int u, int d) {
    int h = u / Ww, w = u - h * Ww;
    if (d == 0) return h * (Ww - 1) + w;
    if (d == 1) return h * (Ww - 1) + w - 1;
    if (d == 2) return EhE + u;
    return EhE + u - Ww;
}

// 64-bit total-order key: (fixed-point weight, edge index)
__device__ __forceinline__ unsigned long long mkkey(double w, int e) {
    unsigned long long q = (unsigned long long)(w * 70368744177664.0);  // 2^46
    if (q >= (1ull << 49)) q = (1ull << 49) - 1;
    return (q << 15) | (unsigned)e;
}

// wave-aggregated compaction push
__device__ __forceinline__ void compact_push(bool keep, int val, int* cnt,
                                             unsigned short* out, int lane) {
    unsigned long long m = __ballot(keep ? 1 : 0);
    if (m == 0ull) return;
    int leader = __ffsll((unsigned long long)m) - 1;
    int base = 0;
    if (lane == leader) base = atomicAdd(cnt, __popcll(m));
    base = __shfl(base, leader, 64);
    if (keep) {
        unsigned long long lower = m & ((1ull << lane) - 1ull);
        out[base + __popcll(lower)] = (unsigned short)val;
    }
}

// inclusive block scan (1024 threads = 16 waves) via shfl; wsum = int[16] LDS
__device__ __forceinline__ int scan1024s(int val, int tid, int* wsum) {
    __syncthreads();                      // protect wsum reuse
    int lane = tid & 63, wv = tid >> 6;
    int x = val;
    #pragma unroll
    for (int off = 1; off < 64; off <<= 1) {
        int y = __shfl_up(x, off, 64);
        if (lane >= off) x += y;
    }
    if (lane == 63) wsum[wv] = x;
    __syncthreads();
    if (wv == 0) {
        int s2 = (lane < 16) ? wsum[lane] : 0;
        #pragma unroll
        for (int off = 1; off < 16; off <<= 1) {
            int y = __shfl_up(s2, off, 64);
            if (lane >= off) s2 += y;
        }
        if (lane < 16) wsum[lane] = s2;
    }
    __syncthreads();
    int base = (wv > 0) ? wsum[wv - 1] : 0;
    return x + base;
}

// legacy scan for k_mst (uses its own bufs)
__device__ __forceinline__ int scan1024_incl(int val, int tid, int* b0, int* b1) {
    b0[tid] = val;
    __syncthreads();
    int* s = b0; int* d = b1;
    for (int off = 1; off < 1024; off <<= 1) {
        int x = s[tid];
        if (tid >= off) x += s[tid - off];
        d[tid] = x;
        __syncthreads();
        int* t = s; s = d; d = t;
    }
    return s[tid];
}

__global__ void k_init(const float* __restrict__ preds, float* __restrict__ prob,
                       double* __restrict__ acc) {
    int idx = blockIdx.x * blockDim.x + threadIdx.x;
    if (idx == 0) { acc[0] = 0.0; acc[1] = 0.0; }
    if (idx >= Bn * Cc * Nn) return;
    prob[idx] = 1.0f / (1.0f + expf(-preds[idx]));
}

// exact float64 edge weights: sequential channel sum matches numpy axis-0 reduce
__global__ void k_edgew(const float* __restrict__ feat, int C, double* __restrict__ ew) {
    int idx = blockIdx.x * blockDim.x + threadIdx.x;
    if (idx >= Bn * Ne) return;
    int b = idx / Ne, e = idx - b * Ne;
    int a, c2; edge_nodes(e, a, c2);
    const float* f = feat + (size_t)b * C * Nn;
    double s = 0.0;
    for (int c = 0; c < C; c++) {
        double d = (double)f[(size_t)c * Nn + a] - (double)f[(size_t)c * Nn + c2];
        s += d * d;
    }
    ew[idx] = s;
}

// Boruvka MST, LDS-resident (R8 version). One block per (tree,batch) tb.
__global__ void __launch_bounds__(1024)
k_mst(char* __restrict__ ws) {
    const int tb = blockIdx.x, tid = threadIdx.x;
    const int lane = tid & 63;
    const double* ew = (const double*)(ws + OFF_EW) + (size_t)tb * Ne;
    int* dirG = (int*)(ws + OFF_DIR) + (size_t)tb * Nn;
    unsigned short* elA = (unsigned short*)(ws + OFF_EL1) + (size_t)tb * Ne;
    unsigned short* elB = (unsigned short*)(ws + OFF_EL2) + (size_t)tb * Ne;

    __shared__ unsigned short comp[Nn];
    __shared__ unsigned long long cbK[MAXC];
    __shared__ int scanBuf[2048];
    __shared__ int chgArr[48];
    __shared__ int sLen, sNC;

    unsigned short* nxtN     = (unsigned short*)cbK;
    unsigned short* newSlotN = (unsigned short*)cbK + Nn;
    unsigned short* nxt      = (unsigned short*)cbK;
    unsigned short* newSlot  = (unsigned short*)cbK + MAXC;

    for (int i = tid; i < Nn; i += 1024) dirG[i] = 0;
    if (tid < 48) chgArr[tid] = 0;
    __syncthreads();

    for (int i = tid; i < Nn; i += 1024) {
        int h = i / Ww, w = i - h * Ww;
        unsigned long long bk = ~0ull;
        if (w < Ww - 1) { int e = h * (Ww - 1) + w;     unsigned long long k = mkkey(ew[e], e); if (k < bk) bk = k; }
        if (w > 0)      { int e = h * (Ww - 1) + w - 1; unsigned long long k = mkkey(ew[e], e); if (k < bk) bk = k; }
        if (h < Hh - 1) { int e = EhE + i;              unsigned long long k = mkkey(ew[e], e); if (k < bk) bk = k; }
        if (h > 0)      { int e = EhE + i - Ww;         unsigned long long k = mkkey(ew[e], e); if (k < bk) bk = k; }
        int e = (int)(bk & 0x7FFF);
        int a, c; edge_nodes(e, a, c);
        nxtN[i] = (unsigned short)((a == i) ? c : a);
        int da = (c == a + 1) ? 0 : 2;
        atomicOr(&dirG[a], 1 << da);
        atomicOr(&dirG[c], 1 << (da ^ 1));
    }
    __syncthreads();
    for (int i = tid; i < Nn; i += 1024) {
        int o = nxtN[i];
        if (o != i && nxtN[o] == i && i < o) nxtN[i] = (unsigned short)i;
    }
    __syncthreads();
    {
        int it = 0;
        while (it < 40) {
            bool any = false;
            for (int r = tid; r < Nn; r += 1024) {
                int nr = nxtN[r], nnr = nxtN[nr];
                if (nr != nnr) { nxtN[r] = (unsigned short)nnr; any = true; }
            }
            if (any) chgArr[it] = 1;
            __syncthreads();
            if (!chgArr[it]) break;
            it++;
        }
    }
    {
        int base = tid * 9, cnt = 0, loc[9];
        #pragma unroll
        for (int k = 0; k < 9; k++) {
            int i = base + k;
            loc[k] = cnt;
            if (nxtN[i] == i) cnt++;
        }
        int incl = scan1024_incl(cnt, tid, scanBuf, scanBuf + 1024);
        int eb = incl - cnt;
        #pragma unroll
        for (int k = 0; k < 9; k++) {
            int i = base + k;
            if (nxtN[i] == i) newSlotN[i] = (unsigned short)(eb + loc[k]);
        }
        if (tid == 1023) sNC = incl;
    }
    __syncthreads();
    for (int i = tid; i < Nn; i += 1024) comp[i] = newSlotN[nxtN[i]];
    __syncthreads();
    int nComp = sNC;

    unsigned short* src = elA;
    unsigned short* dst = elB;
    int srcLen = -1;
    for (int round = 2; round < 22 && nComp > 1; round++) {
        if (tid == 0) sLen = 0;
        if (tid < 48) chgArr[tid] = 0;
        __syncthreads();
        if (srcLen < 0) {
            for (int e = tid; e < Ne; e += 1024) {
                int a, c; edge_nodes(e, a, c);
                compact_push(comp[a] != comp[c], e, &sLen, dst, lane);
            }
        } else {
            for (int k = tid; k < srcLen; k += 1024) {
                int e = src[k];
                int a, c; edge_nodes(e, a, c);
                compact_push(comp[a] != comp[c], e, &sLen, dst, lane);
            }
        }
        for (int s = tid; s < nComp; s += 1024) cbK[s] = ~0ull;
        __syncthreads();
        int len = sLen;
        if (len == 0) break;
        for (int k = tid; k < len; k += 1024) {
            int e = dst[k];
            int a, c; edge_nodes(e, a, c);
            unsigned long long key = mkkey(ew[e], e);
            atomicMin(&cbK[comp[a]], key);
            atomicMin(&cbK[comp[c]], key);
        }
        __syncthreads();
        unsigned long long kr[5];
        int nOwn = 0;
        for (int s = tid; s < nComp; s += 1024) kr[nOwn++] = cbK[s];
        __syncthreads();
        {
            int o = 0;
            for (int s = tid; s < nComp; s += 1024, o++) {
                unsigned long long key = kr[o];
                if (key != ~0ull) {
                    int e = (int)(key & 0x7FFF);
                    int a, c; edge_nodes(e, a, c);
                    int sa = comp[a], sc = comp[c];
                    nxt[s] = (unsigned short)((sa == s) ? sc : sa);
                    int da = (c == a + 1) ? 0 : 2;
                    atomicOr(&dirG[a], 1 << da);
                    atomicOr(&dirG[c], 1 << (da ^ 1));
                } else nxt[s] = (unsigned short)s;
            }
        }
        __syncthreads();
        for (int s = tid; s < nComp; s += 1024) {
            int o = nxt[s];
            if (o != s && nxt[o] == s && s < o) nxt[s] = (unsigned short)s;
        }
        __syncthreads();
        {
            int it = 0;
            while (it < 40) {
                bool any = false;
                for (int s = tid; s < nComp; s += 1024) {
                    int ns = nxt[s], nns = nxt[ns];
                    if (ns != nns) { nxt[s] = (unsigned short)nns; any = true; }
                }
                if (any) chgArr[it] = 1;
                __syncthreads();
                if (!chgArr[it]) break;
                it++;
            }
        }
        {
            int K = (nComp + 1023) >> 10;
            int base = tid * K, cnt = 0, loc[5];
            for (int k = 0; k < K; k++) {
                int s = base + k;
                loc[k] = cnt;
                if (s < nComp && nxt[s] == s) cnt++;
            }
            int incl = scan1024_incl(cnt, tid, scanBuf, scanBuf + 1024);
            int eb = incl - cnt;
            for (int k = 0; k < K; k++) {
                int s = base + k;
                if (s < nComp && nxt[s] == s) newSlot[s] = (unsigned short)(eb + loc[k]);
            }
            if (tid == 1023) sNC = incl;
        }
        __syncthreads();
        for (int i = tid; i < Nn; i += 1024) comp[i] = newSlot[nxt[comp[i]]];
        __syncthreads();
        nComp = sNC;
        unsigned short* t = src; src = dst; dst = t;
        srcLen = len;
    }
}

// Euler-tour topology, R9: rank-space reindex + 3 fused rounds + center walk.
__global__ void __launch_bounds__(1024)
k_topo(char* __restrict__ ws) {
    const int tb = blockIdx.x, tid = threadIdx.x;
    const int lane = tid & 63, wv = tid >> 6;
    const int tree = tb >> 2;
    const double* ew  = (const double*)(ws + OFF_EW) + (size_t)tb * Ne;
    const int*  dirG  = (const int*)(ws + OFF_DIR) + (size_t)tb * Nn;
    unsigned int*   elemSegG = (unsigned int*)(ws + OFF_CBW + (size_t)tb * 73728);
    unsigned short* ORG      = (unsigned short*)(ws + OFF_CBW + (size_t)tb * 73728);      // after P4
    unsigned short* OWNR     = ORG + ESL;
    unsigned short* ownG     = (unsigned short*)(ws + OFF_CBE + (size_t)tb * (size_t)ESL * 2);
    unsigned short* oppG     = (unsigned short*)(ws + OFF_OPP + (size_t)tb * (size_t)ESL * 2);
    unsigned short* IRG      = (unsigned short*)(ws + OFF_SGN + (size_t)tb * ESL);
    unsigned short* rank0G   = (unsigned short*)(ws + OFF_RNK + (size_t)tb * (size_t)ESL * 2);
    int*            ordG  = (int*)(ws + OFF_ORD)  + (size_t)tb * Nn;
    unsigned short* pposG = (unsigned short*)(ws + OFF_PPOS) + (size_t)tb * Nn;
    float*          wgtG  = (float*)(ws + OFF_WGT) + (size_t)tb * Nn;
    int*            levG  = (int*)(ws + OFF_LEV)  + (size_t)tb * MAXD;
    int*            dG    = (int*)(ws + OFF_D);
    const float inv_sigma = tree ? 1.0f : 50.0f;

    __shared__ char A[36864];   // nxtS | rulers(P3) | scanS | final tables
    __shared__ char B[18432];   // degOff -> depthS
    __shared__ char C[9216];    // nbS -> parC
    __shared__ int  wsum[16];
    __shared__ int  sR, sPack, sCenter;

    // ---- P0: masks -> LDS; degree prefix sums ----
    unsigned short* degOff = (unsigned short*)B;
    unsigned char*  nbS    = (unsigned char*)C;
    for (int i = tid; i < Nn; i += 1024) nbS[i] = (unsigned char)dirG[i];
    __syncthreads();
    {
        int base9 = tid * 9;
        int loc[9]; int s = 0;
        #pragma unroll
        for (int k = 0; k < 9; k++) { loc[k] = s; s += __popc(nbS[base9 + k]); }
        int incl = scan1024s(s, tid, wsum);
        int eb = incl - s;
        #pragma unroll
        for (int k = 0; k < 9; k++) degOff[base9 + k] = (unsigned short)(eb + loc[k]);
    }
    __syncthreads();

    // ---- P1: Euler successor + owner + opposite ----
    unsigned short* nxtS = (unsigned short*)A;
    for (int u = tid; u < Nn; u += 1024) {
        int m = nbS[u]; int base = degOff[u]; int k = 0;
        #pragma unroll
        for (int d = 0; d < 4; d++) {
            if (m & (1 << d)) {
                int v = u + dir_delta(d);
                int mv = nbS[v]; int rd = d ^ 1;
                int pv = __popc(mv & ((1 << rd) - 1));
                int dv = __popc(mv);
                int nx = pv + 1; if (nx == dv) nx = 0;
                int j = base + k;
                nxtS[j] = (unsigned short)(degOff[v] + nx);
                ownG[j] = (unsigned short)((u << 2) | d);
                oppG[j] = (unsigned short)(degOff[v] + pv);
                k++;
            }
        }
    }
    __syncthreads();

    // ---- P2: ruling-set walks ----
    int myNr = 0, myLen = 0;
    if (tid < NR) {
        int x = tid * SEG, off = 0;
        for (int g = 0; g < 4096; g++) {
            elemSegG[x] = ((unsigned)tid << 11) | (unsigned)off;
            int y = nxtS[x];
            if (y % SEG == 0) { myNr = y / SEG; myLen = off + 1; break; }
            x = y; off++;
        }
    }
    __syncthreads();

    // ---- P3: ruler pointer doubling (rulers live in C; nbS dead) ----
    unsigned short* cn  = (unsigned short*)C;
    unsigned short* cd  = (unsigned short*)(C + 2048);
    unsigned short* nn2 = (unsigned short*)(C + 4096);
    unsigned short* nd2 = (unsigned short*)(C + 6144);
    if (tid == 0)      { cn[0] = 0; cd[0] = 0; }
    else if (tid < NR) { cn[tid] = (unsigned short)myNr; cd[tid] = (unsigned short)myLen; }
    else               { cn[tid] = (unsigned short)tid; cd[tid] = 0; }
    __syncthreads();
    for (int r = 0; r < 10; r++) {
        int c = cn[tid];
        int dv = cd[tid] + cd[c];
        int n2 = cn[c];
        nn2[tid] = (unsigned short)n2; nd2[tid] = (unsigned short)dv;
        __syncthreads();
        unsigned short* t;
        t = cn; cn = nn2; nn2 = t;
        t = cd; cd = nd2; nd2 = t;
    }
    unsigned short* rb = nn2;
    rb[tid] = (tid == 0) ? 0 : (unsigned short)(TL - cd[tid]);
    __syncthreads();

    // ---- P4: per-element rank0 ----
    for (int e = tid; e < TL; e += 1024) {
        unsigned int pk = elemSegG[e];
        rank0G[e] = (unsigned short)(rb[pk >> 11] + (pk & 2047));
    }
    __syncthreads();

    // ---- P5: rank-space reindex (elemSegG dead -> ORG/OWNR) ----
    for (int j = tid; j < TL; j += 1024) {
        int r = rank0G[j];
        ORG[r]  = rank0G[oppG[j]];
        OWNR[r] = ownG[j];
    }
    for (int x = tid; x < Nn; x += 1024)
        IRG[x] = rank0G[oppG[degOff[x]]];
    __syncthreads();

    // ---- 3 rounds: root 0 -> u -> (v, diam, walk->center) -> center emit ----
    short* scanS = (short*)A;                 // overlays nxtS (dead)
    unsigned char* parC = (unsigned char*)C;  // overlays rulers (dead)
    unsigned short* depthB = (unsigned short*)B;  // overlays degOff (dead after P5)
    int curRoot = 0, rootC = 0;
    for (int ph = 0; ph < 3; ph++) {
        if (tid == 0) {
            sR = ORG[IRG[curRoot]];   // rank0 of root's first out-arc
            sPack = 0;
        }
        __syncthreads();
        const int R = sR;
        const bool doPar = (ph >= 1);
        // fused sign+scan pass over rotated rank positions
        int base = tid * 18;
        int n = TL - base; if (n > 18) n = 18; if (n < 0) n = 0;
        short loc[18]; int s = 0;
        for (int k = 0; k < n; k++) {
            int q = base + k;
            int r = q + R; if (r >= TL) r -= TL;
            int orv = ORG[r];
            int rro = orv - R; if (rro < 0) rro += TL;
            bool desc = q < rro;
            if (doPar && desc) {
                int own = OWNR[r];
                int head = (own >> 2) + dir_delta(own & 3);
                parC[head] = (unsigned char)((own & 3) ^ 1);
            }
            s += desc ? 1 : -1;
            loc[k] = (short)s;
        }
        int incl = scan1024s(s, tid, wsum);
        int eb = incl - s;
        for (int k = 0; k < n; k++) scanS[base + k] = (short)(loc[k] + eb);
        __syncthreads();
        // depth gather + wave-reduced argmax
        int pk = 0;
        for (int x = tid; x < Nn; x += 1024) {
            int q = IRG[x] - R; if (q < 0) q += TL;
            int dep = (x == curRoot) ? 0 : (int)scanS[q];
            int p2 = (dep << 14) | x;
            if (p2 > pk) pk = p2;
            if (ph == 2) depthB[x] = (unsigned short)dep;
        }
        #pragma unroll
        for (int off = 32; off > 0; off >>= 1) {
            int o = __shfl_down(pk, off, 64);
            if (o > pk) pk = o;
        }
        if (lane == 0) atomicMax(&sPack, pk);
        __syncthreads();
        if (ph == 0) curRoot = sPack & 16383;
        else if (ph == 1) {
            if (tid == 0) {
                int diam = sPack >> 14, v = sPack & 16383;
                int steps = diam - (diam >> 1);   // ceil(diam/2) hops from v
                int x = v;
                for (int k2 = 0; k2 < steps; k2++) x += dir_delta(parC[x]);
                sCenter = x;
            }
            __syncthreads();
            curRoot = sCenter;
            rootC = curRoot;
        }
        __syncthreads();   // protect sPack/sR reset next round
    }
    const int D = (sPack >> 14) + 1;

    // ---- counting sort by depth (A free: scanS dead) ----
    unsigned short* posOf = (unsigned short*)A;        // [Nn]
    int* hist   = (int*)(A + 18432);                   // [2048]
    int* levOff = (int*)(A + 26624);                   // [2048]
    for (int k = tid; k < 2048; k += 1024) hist[k] = 0;
    __syncthreads();
    for (int v = tid; v < Nn; v += 1024) atomicAdd(&hist[depthB[v]], 1);
    __syncthreads();
    {
        int h0 = hist[2 * tid], h1 = hist[2 * tid + 1];
        int partial = h0 + h1;
        int incl = scan1024s(partial, tid, wsum);
        int eb = incl - partial;
        levOff[2 * tid] = eb;
        levOff[2 * tid + 1] = eb + h0;
    }
    __syncthreads();
    for (int d = tid; d <= D && d < 2048; d += 1024) levG[d] = levOff[d];
    for (int k = tid; k < 2048; k += 1024) hist[k] = 0;
    __syncthreads();
    for (int v = tid; v < Nn; v += 1024) {
        int dep = depthB[v];
        int pos = levOff[dep] + atomicAdd(&hist[dep], 1);
        posOf[v] = (unsigned short)pos;
        ordG[pos] = v;
    }
    __syncthreads();

    // ---- ppos + filter weights (parC rooted at center) ----
    for (int v = tid; v < Nn; v += 1024) {
        int pos = posOf[v];
        if (v == rootC) { pposG[pos] = 0; wgtG[pos] = 0.0f; }
        else {
            int rd = parC[v];
            int p = v + dir_delta(rd);
            pposG[pos] = posOf[p];
            wgtG[pos] = expf(-(float)ew[edge_of(v, rd)] * inv_sigma);
        }
    }
    if (tid == 0) dG[tb] = D;
}

// Single-wave two-pass tree DP; inMode1 divides by norm channel inline.
__global__ void __launch_bounds__(64)
k_dp(char* __restrict__ ws, int tree, int inMode) {
    const int bc = blockIdx.x;
    const int b = bc / NCh, c = bc % NCh;
    const int tb = tree * Bn + b;
    const int lane = threadIdx.x;
    const int*            ordG  = (const int*)(ws + OFF_ORD)  + (size_t)tb * Nn;
    const unsigned short* pposG = (const unsigned short*)(ws + OFF_PPOS) + (size_t)tb * Nn;
    const float*          wgtG  = (const float*)(ws + OFF_WGT) + (size_t)tb * Nn;
    const int*            levG  = (const int*)(ws + OFF_LEV)  + (size_t)tb * MAXD;
    const int D = ((const int*)(ws + OFF_D))[tb];
    const float* src = (inMode == 0)
        ? (const float*)(ws + OFF_PROB) + ((size_t)b * Cc + c) * Nn
        : (const float*)(ws + OFF_S1)   + ((size_t)b * NCh + c) * Nn;
    const float* srcN = (const float*)(ws + OFF_S1) + ((size_t)b * NCh + Cc) * Nn;
    float* dst = (float*)(ws + (tree ? OFF_S2 : OFF_S1)) + ((size_t)b * NCh + c) * Nn;

    __shared__ alignas(16) float Al[Nn];
    __shared__ alignas(16) unsigned short pposS[Nn];
    __shared__ unsigned short levS[MAXD];

    {
        const uint4* pg4 = (const uint4*)pposG;
        uint4* ps4 = (uint4*)pposS;
        for (int k = lane; k < Nn / 8; k += 64) ps4[k] = pg4[k];
    }
    for (int d = lane; d <= D; d += 64) levS[d] = (unsigned short)levG[d];
    if (c == Cc)            { for (int i = lane; i < Nn; i += 64) Al[i] = 1.0f; }
    else if (inMode == 0)   { for (int i = lane; i < Nn; i += 64) Al[i] = src[ordG[i]]; }
    else                    { for (int i = lane; i < Nn; i += 64) { int nd = ordG[i]; Al[i] = src[nd] / srcN[nd]; } }
    __syncthreads();

    // up: children before parents (ds_add_f32, no return)
    {
        int d = D - 1;
        int s0 = levS[d], s1 = levS[d + 1];
        float wq = (s0 + lane < s1) ? wgtG[s0 + lane] : 0.0f;
        for (; d >= 1; d--) {
            s0 = levS[d]; s1 = levS[d + 1];
            float wq_next = 0.0f;
            if (d > 1) {
                int p0 = levS[d - 1];
                if (p0 + lane < s0) wq_next = wgtG[p0 + lane];
            }
            int i = s0 + lane;
            if (i < s1) atomicAdd(&Al[pposS[i]], wq * Al[i]);
            for (i = s0 + lane + 64; i < s1; i += 64)
                atomicAdd(&Al[pposS[i]], wgtG[i] * Al[i]);
            __syncthreads();
            wq = wq_next;
        }
    }
    // down: parents before children
    if (D > 1) {
        int s0 = levS[1], s1 = levS[2 <= D ? 2 : 1];
        float wq = (s0 + lane < s1) ? wgtG[s0 + lane] : 0.0f;
        for (int d = 1; d < D; d++) {
            s0 = levS[d]; s1 = levS[d + 1];
            float wq_next = 0.0f;
            if (d + 1 < D) {
                int n0 = levS[d + 1], n1 = levS[d + 2];
                if (n0 + lane < n1) wq_next = wgtG[n0 + lane];
            }
            int i = s0 + lane;
            if (i < s1) { float w = wq, a = Al[i]; Al[i] = a + w * (Al[pposS[i]] - w * a); }
            for (i = s0 + lane + 64; i < s1; i += 64) {
                float w = wgtG[i], a = Al[i];
                Al[i] = a + w * (Al[pposS[i]] - w * a);
            }
            __syncthreads();
            wq = wq_next;
        }
    }
    for (int i = lane; i < Nn; i += 64) dst[ordG[i]] = Al[i];
}

__global__ void k_loss(char* __restrict__ ws, const float* __restrict__ roi) {
    const int tid = threadIdx.x;
    int idx = blockIdx.x * 256 + tid;
    const float* prob = (const float*)(ws + OFF_PROB);
    const float* S2   = (const float*)(ws + OFF_S2);
    double* acc = (double*)(ws + OFF_ACC);
    double ls = 0.0, cnt = 0.0;
    if (idx < Bn * Cc * Nn) {
        int b = idx / (Cc * Nn);
        int rem = idx - b * (Cc * Nn);
        int c = rem / Nn, n = rem - c * Nn;
        int h = n / Ww, w2 = n - h * Ww;
        float r = roi[(size_t)b * (2 * Hh) * (2 * Ww) + (size_t)(2 * h) * (2 * Ww) + 2 * w2];
        float as = S2[((size_t)b * NCh + c) * Nn + n] / S2[((size_t)b * NCh + Cc) * Nn + n];
        float pp = prob[((size_t)b * Cc + c) * Nn + n];
        ls = (double)(r * fabsf(pp - as));
        if (c == 0) cnt = (double)r;
    }
    __shared__ double sl[256], sc2[256];
    sl[tid] = ls; sc2[tid] = cnt;
    __syncthreads();
    for (int s = 128; s > 0; s >>= 1) {
        if (tid < s) { sl[tid] += sl[tid + s]; sc2[tid] += sc2[tid + s]; }
        __syncthreads();
    }
    if (tid == 0) { atomicAdd(acc, sl[0]); atomicAdd(acc + 1, sc2[0]); }
}

__global__ void k_final(const double* __restrict__ acc, float* __restrict__ out) {
    if (blockIdx.x == 0 && threadIdx.x == 0)
        out[0] = (acc[1] > 0.0) ? (float)(acc[0] / acc[1]) : 0.0f;
}

extern "C" void kernel_launch(void* const* d_in, const int* in_sizes, int n_in,
                              void* d_out, int out_size, void* d_ws, size_t ws_size,
                              hipStream_t stream) {
    const float* preds = (const float*)d_in[0];
    const float* lowf  = (const float*)d_in[1];
    const float* highf = (const float*)d_in[2];
    const float* roi   = (const float*)d_in[3];
    char* ws = (char*)d_ws;
    float* out = (float*)d_out;
    double* ewl = (double*)(ws + OFF_EW);
    double* ewh = (double*)(ws + OFF_EW) + (size_t)Bn * Ne;

    k_init<<<(Bn * Cc * Nn + 255) / 256, 256, 0, stream>>>(
        preds, (float*)(ws + OFF_PROB), (double*)(ws + OFF_ACC));
    k_edgew<<<(Bn * Ne + 255) / 256, 256, 0, stream>>>(lowf, Clow, ewl);
    k_edgew<<<(Bn * Ne + 255) / 256, 256, 0, stream>>>(highf, Chigh, ewh);
    k_mst<<<8, 1024, 0, stream>>>(ws);
    k_topo<<<8, 1024, 0, stream>>>(ws);
    k_dp<<<Bn * NCh, 64, 0, stream>>>(ws, 0, 0);
    k_dp<<<Bn * NCh, 64, 0, stream>>>(ws, 1, 1);
    k_loss<<<(Bn * Cc * Nn + 255) / 256, 256, 0, stream>>>(ws, roi);
    k_final<<<1, 64, 0, stream>>>((const double*)(ws + OFF_ACC), out);
}